// Round 7
// baseline (175.293 us; speedup 1.0000x reference)
//
#include <hip/hip_runtime.h>

#define TSEQ 4096
#define DM 512
#define NH 8
#define HS 64
#define CTX 256

typedef __attribute__((ext_vector_type(8))) short bf16x8;
typedef __attribute__((ext_vector_type(4))) float f32x4;
typedef unsigned short u16;
typedef unsigned long long ull;

__device__ __forceinline__ u16 f2bf(float x) {
    unsigned u = __float_as_uint(x);
    unsigned r = (u + 0x7fffu + ((u >> 16) & 1u)) >> 16;
    return (u16)r;
}
__device__ __forceinline__ float bf2f(u16 b) {
    return __uint_as_float(((unsigned)b) << 16);
}
__device__ __forceinline__ void split8(const float* v, bf16x8& h, bf16x8& l) {
    #pragma unroll
    for (int i = 0; i < 8; ++i) {
        u16 hb = f2bf(v[i]);
        float hf = bf2f(hb);
        u16 lb = f2bf(v[i] - hf);
        h[i] = (short)hb;
        l[i] = (short)lb;
    }
}
// pack split-bf16 of p into u32 (hi | lo<<16) via v_cvt_pk_bf16_f32
__device__ __forceinline__ unsigned pack_split(float p) {
    unsigned w1;
    asm("v_cvt_pk_bf16_f32 %0, %1, %1" : "=v"(w1) : "v"(p));
    float hf = __uint_as_float(w1 << 16);
    float lo = p - hf;
    unsigned w;
    asm("v_cvt_pk_bf16_f32 %0, %1, %2" : "=v"(w) : "v"(p), "v"(lo));
    return w;
}

#define MFMA(a, b, c) __builtin_amdgcn_mfma_f32_16x16x32_bf16((a), (b), (c), 0, 0, 0)

// ---------------------------------------------------------------------------
__global__ __launch_bounds__(256) void presplit_x(
    const float* __restrict__ X, u16* __restrict__ Xh, u16* __restrict__ Xl)
{
    size_t idx = ((size_t)blockIdx.x * 256 + threadIdx.x) * 8;
    float4 p0 = *(const float4*)(X + idx);
    float4 p1 = *(const float4*)(X + idx + 4);
    float v[8] = {p0.x, p0.y, p0.z, p0.w, p1.x, p1.y, p1.z, p1.w};
    bf16x8 h, l;
    split8(v, h, l);
    *(bf16x8*)(Xh + idx) = h;
    *(bf16x8*)(Xl + idx) = l;
}

// ---------------------------------------------------------------------------
__global__ __launch_bounds__(256) void presplit_w(
    const float* __restrict__ WQ, const float* __restrict__ WV,
    const float* __restrict__ WU,
    u16* __restrict__ WQt_h, u16* __restrict__ WQt_l,
    u16* __restrict__ WVt_h, u16* __restrict__ WVt_l,
    u16* __restrict__ WUt_h, u16* __restrict__ WUt_l)
{
    int gidx = blockIdx.x * 256 + threadIdx.x;   // 0 .. 786431
    int a = gidx >> 18;                          // 0: WQ, 1: WV, 2: WU
    int r = gidx & 262143;
    float val;
    u16 *dh, *dl;
    int dst;
    if (a < 2) {
        int h = r >> 15, s = (r >> 9) & 63, d = r & 511;
        const float* W = (a == 0) ? WQ : WV;
        val = W[h * 32768 + d * 64 + s];
        dst = h * 32768 + s * 512 + d;
        dh = (a == 0) ? WQt_h : WVt_h;
        dl = (a == 0) ? WQt_l : WVt_l;
    } else {
        int n = r >> 9, k = r & 511;
        val = WU[k * 512 + n];
        dst = n * 512 + k;
        dh = WUt_h; dl = WUt_l;
    }
    u16 hb = f2bf(val);
    dh[dst] = hb;
    dl[dst] = f2bf(val - bf2f(hb));
}

// ---------------------------------------------------------------------------
// Split-bf16 MFMA GEMM (unchanged from R6).
// ---------------------------------------------------------------------------
__global__ __launch_bounds__(256) void gemm_mfma(
    const u16* __restrict__ Ah_g, const u16* __restrict__ Al_g,
    const u16* __restrict__ B0h, const u16* __restrict__ B0l,
    const u16* __restrict__ B1h, const u16* __restrict__ B1l,
    u16* __restrict__ O0h, u16* __restrict__ O0l,
    u16* __restrict__ O1h, u16* __restrict__ O1l,
    float* __restrict__ Of,
    int mode)
{
    __shared__ u16 Ah[128][64], Al[128][64];
    __shared__ u16 Bh[64][64],  Bl[64][64];

    const int tid = threadIdx.x;
    const int w = tid >> 6, lane = tid & 63;
    const int lg = lane >> 4, ln = lane & 15;
    const int r0 = blockIdx.x * 128;
    const int y = blockIdx.y;

    const u16 *Bsh, *Bsl;
    if (mode == 0) {
        if (y < 8) { Bsh = B0h + (size_t)y * 32768; Bsl = B0l + (size_t)y * 32768; }
        else       { Bsh = B1h + (size_t)(y - 8) * 32768; Bsl = B1l + (size_t)(y - 8) * 32768; }
    } else {
        Bsh = B0h + (size_t)y * 64 * 512;
        Bsl = B0l + (size_t)y * 64 * 512;
    }

    const int r_a = tid >> 3;
    const int kc  = tid & 7;
    const int wcol = (kc * 8) ^ ((r_a & 7) << 3);
    const size_t gA = (size_t)(r0 + r_a) * DM + kc * 8;
    const size_t gB = (size_t)r_a * 512 + kc * 8;

    bf16x8 a0h, a1h, a2h, a3h, a0l, a1l, a2l, a3l, b0h, b1h, b0l, b1l;

    #define GLOAD(k0)                                                   \
        a0h = *(const bf16x8*)(Ah_g + gA + (k0));                       \
        a1h = *(const bf16x8*)(Ah_g + gA + 32 * DM + (k0));             \
        a2h = *(const bf16x8*)(Ah_g + gA + 64 * DM + (k0));             \
        a3h = *(const bf16x8*)(Ah_g + gA + 96 * DM + (k0));             \
        a0l = *(const bf16x8*)(Al_g + gA + (k0));                       \
        a1l = *(const bf16x8*)(Al_g + gA + 32 * DM + (k0));             \
        a2l = *(const bf16x8*)(Al_g + gA + 64 * DM + (k0));             \
        a3l = *(const bf16x8*)(Al_g + gA + 96 * DM + (k0));             \
        b0h = *(const bf16x8*)(Bsh + gB + (k0));                        \
        b1h = *(const bf16x8*)(Bsh + gB + 32 * 512 + (k0));             \
        b0l = *(const bf16x8*)(Bsl + gB + (k0));                        \
        b1l = *(const bf16x8*)(Bsl + gB + 32 * 512 + (k0));

    f32x4 acc[2][4];
    #pragma unroll
    for (int i = 0; i < 2; ++i)
        #pragma unroll
        for (int j = 0; j < 4; ++j)
            acc[i][j] = (f32x4){0.f, 0.f, 0.f, 0.f};

    GLOAD(0);

    for (int kt = 0; kt < 8; ++kt) {
        __syncthreads();
        *(bf16x8*)&Ah[r_a][wcol]      = a0h;
        *(bf16x8*)&Ah[r_a + 32][wcol] = a1h;
        *(bf16x8*)&Ah[r_a + 64][wcol] = a2h;
        *(bf16x8*)&Ah[r_a + 96][wcol] = a3h;
        *(bf16x8*)&Al[r_a][wcol]      = a0l;
        *(bf16x8*)&Al[r_a + 32][wcol] = a1l;
        *(bf16x8*)&Al[r_a + 64][wcol] = a2l;
        *(bf16x8*)&Al[r_a + 96][wcol] = a3l;
        *(bf16x8*)&Bh[r_a][wcol]      = b0h;
        *(bf16x8*)&Bh[r_a + 32][wcol] = b1h;
        *(bf16x8*)&Bl[r_a][wcol]      = b0l;
        *(bf16x8*)&Bl[r_a + 32][wcol] = b1l;
        __syncthreads();
        if (kt < 7) { GLOAD((kt + 1) * 64); }

        #pragma unroll
        for (int kk = 0; kk < 2; ++kk) {
            const int fc = (kk * 32 + lg * 8) ^ ((ln & 7) << 3);
            bf16x8 ah[2], al[2], bh2[4], bl2[4];
            #pragma unroll
            for (int ti = 0; ti < 2; ++ti) {
                ah[ti] = *(const bf16x8*)&Ah[w * 32 + ti * 16 + ln][fc];
                al[ti] = *(const bf16x8*)&Al[w * 32 + ti * 16 + ln][fc];
            }
            #pragma unroll
            for (int nj = 0; nj < 4; ++nj) {
                bh2[nj] = *(const bf16x8*)&Bh[nj * 16 + ln][fc];
                bl2[nj] = *(const bf16x8*)&Bl[nj * 16 + ln][fc];
            }
            #pragma unroll
            for (int ti = 0; ti < 2; ++ti)
                #pragma unroll
                for (int nj = 0; nj < 4; ++nj) {
                    acc[ti][nj] = MFMA(ah[ti], bh2[nj], acc[ti][nj]);
                    acc[ti][nj] = MFMA(ah[ti], bl2[nj], acc[ti][nj]);
                    acc[ti][nj] = MFMA(al[ti], bh2[nj], acc[ti][nj]);
                }
        }
    }
    #undef GLOAD

    const float qscale = (mode == 0 && y < 8) ? 0.125f : 1.0f;
    #pragma unroll
    for (int ti = 0; ti < 2; ++ti)
        #pragma unroll
        for (int nj = 0; nj < 4; ++nj)
            #pragma unroll
            for (int r = 0; r < 4; ++r) {
                float val = acc[ti][nj][r] * qscale;
                int t = r0 + w * 32 + ti * 16 + lg * 4 + r;
                int n = nj * 16 + ln;
                if (mode == 0) {
                    int bh = (t >> 12) * NH + (y & 7);
                    size_t off = ((size_t)bh * TSEQ + (t & (TSEQ - 1))) * HS + n;
                    u16 hb = f2bf(val);
                    u16 lb = f2bf(val - bf2f(hb));
                    if (y < 8) { O0h[off] = hb; O0l[off] = lb; }
                    else       { O1h[off] = hb; O1l[off] = lb; }
                } else {
                    Of[(size_t)t * DM + y * 64 + n] = val;
                }
            }
}

// ---------------------------------------------------------------------------
// V transpose: Vn[bh][u][s] -> Vt[bh][s][u], hi and lo planes. LDS-tiled.
// ---------------------------------------------------------------------------
__global__ __launch_bounds__(256) void transpose_v(
    const u16* __restrict__ Vnh, const u16* __restrict__ Vnl,
    u16* __restrict__ Vth, u16* __restrict__ Vtl)
{
    __shared__ u16 T[64][72];

    const int tid = threadIdx.x;
    const int bh = blockIdx.x >> 6;
    const int u0 = (blockIdx.x & 63) * 64;
    const size_t base = (size_t)bh * TSEQ * HS;

    const int lu = tid >> 2;            // 0..63 (load row)
    const int s8 = (tid & 3) * 16;      // load col block
    const int so = tid >> 2;            // 0..63 (store row = s)
    const int u8 = (tid & 3) * 16;      // store col block

    #pragma unroll
    for (int plane = 0; plane < 2; ++plane) {
        const u16* src = plane ? Vnl : Vnh;
        u16* dst = plane ? Vtl : Vth;
        size_t goff = base + (size_t)(u0 + lu) * HS + s8;
        bf16x8 v0 = *(const bf16x8*)(src + goff);
        bf16x8 v1 = *(const bf16x8*)(src + goff + 8);
        *(bf16x8*)&T[lu][s8]     = v0;
        *(bf16x8*)&T[lu][s8 + 8] = v1;
        __syncthreads();
        union { u16 a[16]; bf16x8 v[2]; } out;
        #pragma unroll
        for (int e = 0; e < 16; ++e)
            out.a[e] = T[u8 + e][so];
        size_t doff = base + (size_t)so * TSEQ + u0 + u8;
        *(bf16x8*)(dst + doff)     = out.v[0];
        *(bf16x8*)(dst + doff + 8) = out.v[1];
        __syncthreads();
    }
}

// ---------------------------------------------------------------------------
// Barrier-free banded flash attention: one wave (64 thr) per 32 t-rows.
// Q register-resident; QK and PV V-fragments read directly from global
// (L2-resident); only LDS use is the 4 KB per-wave P tile (same-wave DS).
// ---------------------------------------------------------------------------
__global__ __launch_bounds__(64) void attn_g(
    const u16* __restrict__ Qh_g, const u16* __restrict__ Ql_g,
    const u16* __restrict__ Vnh_g, const u16* __restrict__ Vnl_g,
    const u16* __restrict__ Vth_g, const u16* __restrict__ Vtl_g,
    u16* __restrict__ Ch, u16* __restrict__ Cl)
{
    __shared__ unsigned Ps[32][32];     // [t][(u&31) ^ ((t&7)<<2)] hi|lo<<16

    const int lane = threadIdx.x;
    const int lg = lane >> 4, ln = lane & 15;
    int bid = blockIdx.x;
    bid = (bid & 7) * 256 + (bid >> 3);          // XCD-contiguous (2048 % 8 == 0)
    const int ttile = bid & 127;
    const int bh = bid >> 7;
    const int t0 = ttile * 32;

    const u16* Qph = Qh_g + (size_t)bh * TSEQ * HS;
    const u16* Qpl = Ql_g + (size_t)bh * TSEQ * HS;
    const u16* Vnh = Vnh_g + (size_t)bh * TSEQ * HS;
    const u16* Vnl = Vnl_g + (size_t)bh * TSEQ * HS;
    const u16* Vth = Vth_g + (size_t)bh * TSEQ * HS;
    const u16* Vtl = Vtl_g + (size_t)bh * TSEQ * HS;

    // Q fragments (prescaled by 1/8 at projection)
    bf16x8 qh[2][2], ql[2][2];
    #pragma unroll
    for (int ti = 0; ti < 2; ++ti)
        #pragma unroll
        for (int kk = 0; kk < 2; ++kk) {
            size_t off = (size_t)(t0 + ti * 16 + ln) * HS + kk * 32 + lg * 8;
            qh[ti][kk] = *(const bf16x8*)(Qph + off);
            ql[ti][kk] = *(const bf16x8*)(Qpl + off);
        }

    f32x4 o[2][4];
    float m[2][4], lsum[2][4];
    #pragma unroll
    for (int ti = 0; ti < 2; ++ti)
        #pragma unroll
        for (int j = 0; j < 4; ++j) {
            o[ti][j] = (f32x4){0.f, 0.f, 0.f, 0.f};
            m[ti][j] = -1e30f;
            lsum[ti][j] = 0.f;
        }

    int u_lo = t0 - CTX; if (u_lo < 0) u_lo = 0; u_lo &= ~63;
    int u_hi = t0 + 32 + CTX; u_hi = (u_hi + 63) & ~63; if (u_hi > TSEQ) u_hi = TSEQ;

    for (int u0 = u_lo; u0 < u_hi; u0 += 64) {
        // ---- scores: S[t][u] = sum_s Q[t][s] V[u][s], V frags from global
        f32x4 s[2][4];
        #pragma unroll
        for (int ti = 0; ti < 2; ++ti)
            #pragma unroll
            for (int j = 0; j < 4; ++j)
                s[ti][j] = (f32x4){0.f, 0.f, 0.f, 0.f};

        #pragma unroll
        for (int kk = 0; kk < 2; ++kk) {
            bf16x8 vh[4], vl[4];
            #pragma unroll
            for (int uj = 0; uj < 4; ++uj) {
                size_t off = (size_t)(u0 + uj * 16 + ln) * HS + kk * 32 + lg * 8;
                vh[uj] = *(const bf16x8*)(Vnh + off);
                vl[uj] = *(const bf16x8*)(Vnl + off);
            }
            #pragma unroll
            for (int ti = 0; ti < 2; ++ti)
                #pragma unroll
                for (int uj = 0; uj < 4; ++uj) {
                    s[ti][uj] = MFMA(qh[ti][kk], vh[uj], s[ti][uj]);
                    s[ti][uj] = MFMA(qh[ti][kk], vl[uj], s[ti][uj]);
                    s[ti][uj] = MFMA(ql[ti][kk], vh[uj], s[ti][uj]);
                }
        }

        // ---- band mask
        bool needmask = ((t0 + 31 - u0) > CTX) || ((u0 + 63 - t0) > CTX);
        if (needmask) {
            #pragma unroll
            for (int ti = 0; ti < 2; ++ti)
                #pragma unroll
                for (int uj = 0; uj < 4; ++uj)
                    #pragma unroll
                    for (int r = 0; r < 4; ++r) {
                        int t = t0 + ti * 16 + lg * 4 + r;
                        int u = u0 + uj * 16 + ln;
                        int d = t - u; if (d < 0) d = -d;
                        if (d > CTX) s[ti][uj][r] = -1e30f;
                    }
        }

        // ---- online softmax per row (16-lane ln reduction)
        float scl[2][4];
        #pragma unroll
        for (int ti = 0; ti < 2; ++ti)
            #pragma unroll
            for (int r = 0; r < 4; ++r) {
                float rm = fmaxf(fmaxf(s[ti][0][r], s[ti][1][r]),
                                 fmaxf(s[ti][2][r], s[ti][3][r]));
                rm = fmaxf(rm, __shfl_xor(rm, 1));
                rm = fmaxf(rm, __shfl_xor(rm, 2));
                rm = fmaxf(rm, __shfl_xor(rm, 4));
                rm = fmaxf(rm, __shfl_xor(rm, 8));
                float mn = fmaxf(m[ti][r], rm);
                float sc2 = __expf(m[ti][r] - mn);
                m[ti][r] = mn;
                scl[ti][r] = sc2;
                float rs = 0.f;
                #pragma unroll
                for (int uj = 0; uj < 4; ++uj) {
                    float p = __expf(s[ti][uj][r] - mn);
                    s[ti][uj][r] = p;
                    rs += p;
                }
                rs += __shfl_xor(rs, 1);
                rs += __shfl_xor(rs, 2);
                rs += __shfl_xor(rs, 4);
                rs += __shfl_xor(rs, 8);
                lsum[ti][r] = lsum[ti][r] * sc2 + rs;
            }

        // ---- rescale running O
        #pragma unroll
        for (int ti = 0; ti < 2; ++ti)
            #pragma unroll
            for (int sj = 0; sj < 4; ++sj)
                #pragma unroll
                for (int r = 0; r < 4; ++r)
                    o[ti][sj][r] *= scl[ti][r];

        // ---- PV in two u-halves; P strip same-wave LDS roundtrip
        #pragma unroll
        for (int kk = 0; kk < 2; ++kk) {
            #pragma unroll
            for (int ti = 0; ti < 2; ++ti)
                #pragma unroll
                for (int u2 = 0; u2 < 2; ++u2) {
                    int uj = kk * 2 + u2;
                    #pragma unroll
                    for (int r = 0; r < 4; ++r) {
                        int trow = ti * 16 + lg * 4 + r;
                        int ucol = (u2 * 16 + ln) ^ ((trow & 7) << 2);
                        Ps[trow][ucol] = pack_split(s[ti][uj][r]);
                    }
                }

            bf16x8 ph[2], pl[2], vth[4], vtl[4];
            #pragma unroll
            for (int ti = 0; ti < 2; ++ti) {
                int prow = ti * 16 + ln;
                int sw = (ln & 7) << 2;
                uint4 q0 = *(const uint4*)&Ps[prow][(lg * 8) ^ sw];
                uint4 q1 = *(const uint4*)&Ps[prow][(lg * 8 + 4) ^ sw];
                union { unsigned u[4]; bf16x8 v; } H, L;
                H.u[0] = __builtin_amdgcn_perm(q0.y, q0.x, 0x05040100u);
                H.u[1] = __builtin_amdgcn_perm(q0.w, q0.z, 0x05040100u);
                H.u[2] = __builtin_amdgcn_perm(q1.y, q1.x, 0x05040100u);
                H.u[3] = __builtin_amdgcn_perm(q1.w, q1.z, 0x05040100u);
                L.u[0] = __builtin_amdgcn_perm(q0.y, q0.x, 0x07060302u);
                L.u[1] = __builtin_amdgcn_perm(q0.w, q0.z, 0x07060302u);
                L.u[2] = __builtin_amdgcn_perm(q1.y, q1.x, 0x07060302u);
                L.u[3] = __builtin_amdgcn_perm(q1.w, q1.z, 0x07060302u);
                ph[ti] = H.v;
                pl[ti] = L.v;
            }
            #pragma unroll
            for (int sj = 0; sj < 4; ++sj) {
                size_t off = (size_t)(sj * 16 + ln) * TSEQ + u0 + kk * 32 + lg * 8;
                vth[sj] = *(const bf16x8*)(Vth + off);
                vtl[sj] = *(const bf16x8*)(Vtl + off);
            }
            #pragma unroll
            for (int ti = 0; ti < 2; ++ti)
                #pragma unroll
                for (int sj = 0; sj < 4; ++sj) {
                    o[ti][sj] = MFMA(ph[ti], vth[sj], o[ti][sj]);
                    o[ti][sj] = MFMA(ph[ti], vtl[sj], o[ti][sj]);
                    o[ti][sj] = MFMA(pl[ti], vth[sj], o[ti][sj]);
                }
        }
    }

    // ---- epilogue: C split bf16, layout [b][t][h*64+s]
    const int b = bh >> 3, h = bh & 7;
    #pragma unroll
    for (int ti = 0; ti < 2; ++ti)
        #pragma unroll
        for (int r = 0; r < 4; ++r) {
            float inv = 1.f / lsum[ti][r];
            int t = t0 + ti * 16 + lg * 4 + r;
            #pragma unroll
            for (int sj = 0; sj < 4; ++sj) {
                int ss = sj * 16 + ln;
                float val = o[ti][sj][r] * inv;
                size_t off = ((size_t)(b * TSEQ + t)) * DM + h * HS + ss;
                u16 hb = f2bf(val);
                Ch[off] = hb;
                Cl[off] = f2bf(val - bf2f(hb));
            }
        }
}

// ---------------------------------------------------------------------------
// Fallback attention (R6, proven): used only if ws_size is too small for Vt.
// ---------------------------------------------------------------------------
__global__ __launch_bounds__(256) void attn_mfma(
    const u16* __restrict__ Qh_g, const u16* __restrict__ Ql_g,
    const u16* __restrict__ Vh_g, const u16* __restrict__ Vl_g,
    u16* __restrict__ Ch, u16* __restrict__ Cl)
{
    __shared__ u16 Vn_h[64][64], Vn_l[64][64];
    __shared__ u16 Vt_h[64][64], Vt_l[64][64];
    __shared__ unsigned Ps[128][32];

    const int tid = threadIdx.x;
    const int w = tid >> 6, lane = tid & 63;
    const int lg = lane >> 4, ln = lane & 15;
    const int ttile = blockIdx.x & 31;
    const int bh = blockIdx.x >> 5;
    const int t0 = ttile * 128;
    const u16* Qph = Qh_g + (size_t)bh * TSEQ * HS;
    const u16* Qpl = Ql_g + (size_t)bh * TSEQ * HS;
    const u16* Vph = Vh_g + (size_t)bh * TSEQ * HS;
    const u16* Vpl = Vl_g + (size_t)bh * TSEQ * HS;

    bf16x8 qh[2][2], ql[2][2];
    #pragma unroll
    for (int ti = 0; ti < 2; ++ti)
        #pragma unroll
        for (int kk = 0; kk < 2; ++kk) {
            int trow = t0 + w * 32 + ti * 16 + ln;
            size_t off = (size_t)trow * HS + kk * 32 + lg * 8;
            qh[ti][kk] = *(const bf16x8*)(Qph + off);
            ql[ti][kk] = *(const bf16x8*)(Qpl + off);
        }

    f32x4 o[2][4];
    float m[2][4], lsum[2][4];
    #pragma unroll
    for (int ti = 0; ti < 2; ++ti)
        #pragma unroll
        for (int j = 0; j < 4; ++j) {
            o[ti][j] = (f32x4){0.f, 0.f, 0.f, 0.f};
            m[ti][j] = -1e30f;
            lsum[ti][j] = 0.f;
        }

    int u_lo = t0 - CTX; if (u_lo < 0) u_lo = 0;
    int u_hi = t0 + 128 + CTX; if (u_hi > TSEQ) u_hi = TSEQ;

    const int u_r = tid >> 3;
    const int sc  = tid & 7;
    const size_t gV = (size_t)u_r * HS + sc * 8;

    bf16x8 vf0h, vf1h, vf0l, vf1l;
    #define V_LOAD(u0v)                                                   \
        vf0h = *(const bf16x8*)(Vph + (size_t)(u0v) * HS + gV);           \
        vf1h = *(const bf16x8*)(Vph + (size_t)(u0v) * HS + gV + 32 * HS); \
        vf0l = *(const bf16x8*)(Vpl + (size_t)(u0v) * HS + gV);           \
        vf1l = *(const bf16x8*)(Vpl + (size_t)(u0v) * HS + gV + 32 * HS);

    V_LOAD(u_lo);

    const int wcolV = (sc * 8) ^ ((u_r & 7) << 3);

    for (int u0 = u_lo; u0 < u_hi; u0 += 64) {
        __syncthreads();
        *(bf16x8*)&Vn_h[u_r][wcolV]      = vf0h;
        *(bf16x8*)&Vn_h[u_r + 32][wcolV] = vf1h;
        *(bf16x8*)&Vn_l[u_r][wcolV]      = vf0l;
        *(bf16x8*)&Vn_l[u_r + 32][wcolV] = vf1l;
        {
            union { bf16x8 v; ull q[2]; } h0, h1, l0, l1;
            h0.v = vf0h; h1.v = vf1h; l0.v = vf0l; l1.v = vf1l;
            #pragma unroll
            for (int e = 0; e < 8; ++e) {
                int j = (sc + e) & 7;
                int sh = (j & 3) * 16;
                int row = sc * 8 + j;
                ull sh0 = (j & 4) ? h0.q[1] : h0.q[0];
                ull sl0 = (j & 4) ? l0.q[1] : l0.q[0];
                ull sh1 = (j & 4) ? h1.q[1] : h1.q[0];
                ull sl1 = (j & 4) ? l1.q[1] : l1.q[0];
                Vt_h[row][u_r ^ (j << 3)]        = (u16)(sh0 >> sh);
                Vt_l[row][u_r ^ (j << 3)]        = (u16)(sl0 >> sh);
                Vt_h[row][(u_r + 32) ^ (j << 3)] = (u16)(sh1 >> sh);
                Vt_l[row][(u_r + 32) ^ (j << 3)] = (u16)(sl1 >> sh);
            }
        }
        __syncthreads();
        if (u0 + 64 < u_hi) { V_LOAD(u0 + 64); }

        f32x4 s[2][4];
        #pragma unroll
        for (int ti = 0; ti < 2; ++ti)
            #pragma unroll
            for (int j = 0; j < 4; ++j)
                s[ti][j] = (f32x4){0.f, 0.f, 0.f, 0.f};

        #pragma unroll
        for (int kk = 0; kk < 2; ++kk) {
            const int fc = (kk * 32 + lg * 8) ^ ((ln & 7) << 3);
            bf16x8 vh[4], vl[4];
            #pragma unroll
            for (int uj = 0; uj < 4; ++uj) {
                vh[uj] = *(const bf16x8*)&Vn_h[uj * 16 + ln][fc];
                vl[uj] = *(const bf16x8*)&Vn_l[uj * 16 + ln][fc];
            }
            #pragma unroll
            for (int ti = 0; ti < 2; ++ti)
                #pragma unroll
                for (int uj = 0; uj < 4; ++uj) {
                    s[ti][uj] = MFMA(qh[ti][kk], vh[uj], s[ti][uj]);
                    s[ti][uj] = MFMA(qh[ti][kk], vl[uj], s[ti][uj]);
                    s[ti][uj] = MFMA(ql[ti][kk], vh[uj], s[ti][uj]);
                }
        }

        bool needmask = ((t0 + 127 - u0) > CTX) || ((u0 + 63 - t0) > CTX);
        if (needmask) {
            #pragma unroll
            for (int ti = 0; ti < 2; ++ti)
                #pragma unroll
                for (int uj = 0; uj < 4; ++uj)
                    #pragma unroll
                    for (int r = 0; r < 4; ++r) {
                        int t = t0 + w * 32 + ti * 16 + lg * 4 + r;
                        int u = u0 + uj * 16 + ln;
                        int d = t - u; if (d < 0) d = -d;
                        if (d > CTX) s[ti][uj][r] = -1e30f;
                    }
        }

        float scl[2][4];
        #pragma unroll
        for (int ti = 0; ti < 2; ++ti)
            #pragma unroll
            for (int r = 0; r < 4; ++r) {
                float rm = fmaxf(fmaxf(s[ti][0][r], s[ti][1][r]),
                                 fmaxf(s[ti][2][r], s[ti][3][r]));
                rm = fmaxf(rm, __shfl_xor(rm, 1));
                rm = fmaxf(rm, __shfl_xor(rm, 2));
                rm = fmaxf(rm, __shfl_xor(rm, 4));
                rm = fmaxf(rm, __shfl_xor(rm, 8));
                float mn = fmaxf(m[ti][r], rm);
                float sc2 = __expf(m[ti][r] - mn);
                m[ti][r] = mn;
                scl[ti][r] = sc2;
                float rs = 0.f;
                #pragma unroll
                for (int uj = 0; uj < 4; ++uj) {
                    float p = __expf(s[ti][uj][r] - mn);
                    s[ti][uj][r] = p;
                    rs += p;
                }
                rs += __shfl_xor(rs, 1);
                rs += __shfl_xor(rs, 2);
                rs += __shfl_xor(rs, 4);
                rs += __shfl_xor(rs, 8);
                lsum[ti][r] = lsum[ti][r] * sc2 + rs;
            }

        #pragma unroll
        for (int ti = 0; ti < 2; ++ti)
            #pragma unroll
            for (int sj = 0; sj < 4; ++sj)
                #pragma unroll
                for (int r = 0; r < 4; ++r)
                    o[ti][sj][r] *= scl[ti][r];

        #pragma unroll
        for (int kk = 0; kk < 2; ++kk) {
            #pragma unroll
            for (int ti = 0; ti < 2; ++ti)
                #pragma unroll
                for (int u2 = 0; u2 < 2; ++u2) {
                    int uj = kk * 2 + u2;
                    #pragma unroll
                    for (int r = 0; r < 4; ++r) {
                        int trow = w * 32 + ti * 16 + lg * 4 + r;
                        int ucol = (u2 * 16 + ln) ^ ((trow & 7) << 2);
                        Ps[trow][ucol] = pack_split(s[ti][uj][r]);
                    }
                }

            bf16x8 ph[2], pl[2], vth[4], vtl[4];
            #pragma unroll
            for (int ti = 0; ti < 2; ++ti) {
                int prow = w * 32 + ti * 16 + ln;
                int sw = (ln & 7) << 2;
                uint4 q0 = *(const uint4*)&Ps[prow][(lg * 8) ^ sw];
                uint4 q1 = *(const uint4*)&Ps[prow][(lg * 8 + 4) ^ sw];
                union { unsigned u[4]; bf16x8 v; } H, L;
                H.u[0] = __builtin_amdgcn_perm(q0.y, q0.x, 0x05040100u);
                H.u[1] = __builtin_amdgcn_perm(q0.w, q0.z, 0x05040100u);
                H.u[2] = __builtin_amdgcn_perm(q1.y, q1.x, 0x05040100u);
                H.u[3] = __builtin_amdgcn_perm(q1.w, q1.z, 0x05040100u);
                L.u[0] = __builtin_amdgcn_perm(q0.y, q0.x, 0x07060302u);
                L.u[1] = __builtin_amdgcn_perm(q0.w, q0.z, 0x07060302u);
                L.u[2] = __builtin_amdgcn_perm(q1.y, q1.x, 0x07060302u);
                L.u[3] = __builtin_amdgcn_perm(q1.w, q1.z, 0x07060302u);
                ph[ti] = H.v;
                pl[ti] = L.v;
            }
            const int fct = (kk * 32 + lg * 8) ^ ((ln & 7) << 3);
            #pragma unroll
            for (int sj = 0; sj < 4; ++sj) {
                vth[sj] = *(const bf16x8*)&Vt_h[sj * 16 + ln][fct];
                vtl[sj] = *(const bf16x8*)&Vt_l[sj * 16 + ln][fct];
            }
            #pragma unroll
            for (int ti = 0; ti < 2; ++ti)
                #pragma unroll
                for (int sj = 0; sj < 4; ++sj) {
                    o[ti][sj] = MFMA(ph[ti], vth[sj], o[ti][sj]);
                    o[ti][sj] = MFMA(ph[ti], vtl[sj], o[ti][sj]);
                    o[ti][sj] = MFMA(pl[ti], vth[sj], o[ti][sj]);
                }
        }
    }
    #undef V_LOAD

    const int b = bh >> 3, h = bh & 7;
    #pragma unroll
    for (int ti = 0; ti < 2; ++ti)
        #pragma unroll
        for (int r = 0; r < 4; ++r) {
            float inv = 1.f / lsum[ti][r];
            int t = t0 + w * 32 + ti * 16 + lg * 4 + r;
            #pragma unroll
            for (int sj = 0; sj < 4; ++sj) {
                int ss = sj * 16 + ln;
                float val = o[ti][sj][r] * inv;
                size_t off = ((size_t)(b * TSEQ + t)) * DM + h * HS + ss;
                u16 hb = f2bf(val);
                Ch[off] = hb;
                Cl[off] = f2bf(val - bf2f(hb));
            }
        }
}

// ---------------------------------------------------------------------------
extern "C" void kernel_launch(void* const* d_in, const int* in_sizes, int n_in,
                              void* d_out, int out_size, void* d_ws, size_t ws_size,
                              hipStream_t stream) {
    const float* X  = (const float*)d_in[0];
    const float* WQ = (const float*)d_in[1];
    const float* WV = (const float*)d_in[2];
    const float* WU = (const float*)d_in[3];
    float* out = (float*)d_out;

    const size_t SZ = 8388608;   // 8 MB region
    char* ws = (char*)d_ws;
    const bool fast = ws_size >= (size_t)(8 * SZ + 6 * 524288);

    u16* Xh = (u16*)(ws);             // later reused as Ch
    u16* Xl = (u16*)(ws + SZ);        // later reused as Cl
    u16* Qh = (u16*)(ws + 2 * SZ);
    u16* Ql = (u16*)(ws + 3 * SZ);
    u16* Vh = (u16*)(ws + 4 * SZ);
    u16* Vl = (u16*)(ws + 5 * SZ);
    u16* Vth = (u16*)(ws + 6 * SZ);   // fast path only
    u16* Vtl = (u16*)(ws + 7 * SZ);
    char* wsw = ws + (fast ? 8 * SZ : 6 * SZ);
    u16* WQt_h = (u16*)(wsw);
    u16* WQt_l = (u16*)(wsw + 524288);
    u16* WVt_h = (u16*)(wsw + 2 * 524288);
    u16* WVt_l = (u16*)(wsw + 3 * 524288);
    u16* WUt_h = (u16*)(wsw + 4 * 524288);
    u16* WUt_l = (u16*)(wsw + 5 * 524288);

    presplit_x<<<2048, 256, 0, stream>>>(X, Xh, Xl);
    presplit_w<<<3072, 256, 0, stream>>>(WQ, WV, WU, WQt_h, WQt_l,
                                         WVt_h, WVt_l, WUt_h, WUt_l);
    gemm_mfma<<<dim3(64, 16), 256, 0, stream>>>(
        Xh, Xl, WQt_h, WQt_l, WVt_h, WVt_l, Qh, Ql, Vh, Vl, nullptr, 0);
    if (fast) {
        transpose_v<<<1024, 256, 0, stream>>>(Vh, Vl, Vth, Vtl);
        attn_g<<<2048, 64, 0, stream>>>(Qh, Ql, Vh, Vl, Vth, Vtl, Xh, Xl);
    } else {
        attn_mfma<<<512, 256, 0, stream>>>(Qh, Ql, Vh, Vl, Xh, Xl);
    }
    gemm_mfma<<<dim3(64, 8), 256, 0, stream>>>(
        Xh, Xl, WUt_h, WUt_l, nullptr, nullptr,
        nullptr, nullptr, nullptr, nullptr, out, 1);
}

// Round 9
// 151.604 us; speedup vs baseline: 1.1563x; 1.1563x over previous
//
#include <hip/hip_runtime.h>

#define TSEQ 4096
#define DM 512
#define NH 8
#define HS 64
#define CTX 256

typedef __attribute__((ext_vector_type(8))) short bf16x8;
typedef __attribute__((ext_vector_type(4))) float f32x4;
typedef unsigned short u16;
typedef unsigned long long ull;

__device__ __forceinline__ u16 f2bf(float x) {
    unsigned u = __float_as_uint(x);
    unsigned r = (u + 0x7fffu + ((u >> 16) & 1u)) >> 16;
    return (u16)r;
}
__device__ __forceinline__ float bf2f(u16 b) {
    return __uint_as_float(((unsigned)b) << 16);
}
// pack split-bf16 of p into u32 (hi | lo<<16) via v_cvt_pk_bf16_f32 (R7-proven)
__device__ __forceinline__ unsigned pack_split(float p) {
    unsigned w1;
    asm("v_cvt_pk_bf16_f32 %0, %1, %1" : "=v"(w1) : "v"(p));
    float hf = __uint_as_float(w1 << 16);
    float lo = p - hf;
    unsigned w;
    asm("v_cvt_pk_bf16_f32 %0, %1, %2" : "=v"(w) : "v"(p), "v"(lo));
    return w;
}
__device__ __forceinline__ void split8(const float* v, bf16x8& h, bf16x8& l) {
    #pragma unroll
    for (int i = 0; i < 8; ++i) {
        u16 hb = f2bf(v[i]);
        float hf = bf2f(hb);
        u16 lb = f2bf(v[i] - hf);
        h[i] = (short)hb;
        l[i] = (short)lb;
    }
}

#define MFMA(a, b, c) __builtin_amdgcn_mfma_f32_16x16x32_bf16((a), (b), (c), 0, 0, 0)

// ---------------------------------------------------------------------------
__global__ __launch_bounds__(256) void presplit_x(
    const float* __restrict__ X, u16* __restrict__ Xh, u16* __restrict__ Xl)
{
    size_t idx = ((size_t)blockIdx.x * 256 + threadIdx.x) * 8;
    float4 p0 = *(const float4*)(X + idx);
    float4 p1 = *(const float4*)(X + idx + 4);
    float v[8] = {p0.x, p0.y, p0.z, p0.w, p1.x, p1.y, p1.z, p1.w};
    bf16x8 h, l;
    split8(v, h, l);
    *(bf16x8*)(Xh + idx) = h;
    *(bf16x8*)(Xl + idx) = l;
}

// ---------------------------------------------------------------------------
__global__ __launch_bounds__(256) void presplit_w(
    const float* __restrict__ WQ, const float* __restrict__ WV,
    const float* __restrict__ WU,
    u16* __restrict__ WQt_h, u16* __restrict__ WQt_l,
    u16* __restrict__ WVt_h, u16* __restrict__ WVt_l,
    u16* __restrict__ WUt_h, u16* __restrict__ WUt_l)
{
    int gidx = blockIdx.x * 256 + threadIdx.x;   // 0 .. 786431
    int a = gidx >> 18;                          // 0: WQ, 1: WV, 2: WU
    int r = gidx & 262143;
    float val;
    u16 *dh, *dl;
    int dst;
    if (a < 2) {
        int h = r >> 15, s = (r >> 9) & 63, d = r & 511;
        const float* W = (a == 0) ? WQ : WV;
        val = W[h * 32768 + d * 64 + s];
        dst = h * 32768 + s * 512 + d;
        dh = (a == 0) ? WQt_h : WVt_h;
        dl = (a == 0) ? WQt_l : WVt_l;
    } else {
        int n = r >> 9, k = r & 511;
        val = WU[k * 512 + n];
        dst = n * 512 + k;
        dh = WUt_h; dl = WUt_l;
    }
    u16 hb = f2bf(val);
    dh[dst] = hb;
    dl[dst] = f2bf(val - bf2f(hb));
}

// ---------------------------------------------------------------------------
// Split-bf16 MFMA GEMM (R6, proven). 128x64 tile, K=512, BK=64.
// ---------------------------------------------------------------------------
__global__ __launch_bounds__(256) void gemm_mfma(
    const u16* __restrict__ Ah_g, const u16* __restrict__ Al_g,
    const u16* __restrict__ B0h, const u16* __restrict__ B0l,
    const u16* __restrict__ B1h, const u16* __restrict__ B1l,
    u16* __restrict__ O0h, u16* __restrict__ O0l,
    u16* __restrict__ O1h, u16* __restrict__ O1l,
    float* __restrict__ Of,
    int mode)
{
    __shared__ u16 Ah[128][64], Al[128][64];
    __shared__ u16 Bh[64][64],  Bl[64][64];

    const int tid = threadIdx.x;
    const int w = tid >> 6, lane = tid & 63;
    const int lg = lane >> 4, ln = lane & 15;
    const int r0 = blockIdx.x * 128;
    const int y = blockIdx.y;

    const u16 *Bsh, *Bsl;
    if (mode == 0) {
        if (y < 8) { Bsh = B0h + (size_t)y * 32768; Bsl = B0l + (size_t)y * 32768; }
        else       { Bsh = B1h + (size_t)(y - 8) * 32768; Bsl = B1l + (size_t)(y - 8) * 32768; }
    } else {
        Bsh = B0h + (size_t)y * 64 * 512;
        Bsl = B0l + (size_t)y * 64 * 512;
    }

    const int r_a = tid >> 3;
    const int kc  = tid & 7;
    const int wcol = (kc * 8) ^ ((r_a & 7) << 3);
    const size_t gA = (size_t)(r0 + r_a) * DM + kc * 8;
    const size_t gB = (size_t)r_a * 512 + kc * 8;

    bf16x8 a0h, a1h, a2h, a3h, a0l, a1l, a2l, a3l, b0h, b1h, b0l, b1l;

    #define GLOAD(k0)                                                   \
        a0h = *(const bf16x8*)(Ah_g + gA + (k0));                       \
        a1h = *(const bf16x8*)(Ah_g + gA + 32 * DM + (k0));             \
        a2h = *(const bf16x8*)(Ah_g + gA + 64 * DM + (k0));             \
        a3h = *(const bf16x8*)(Ah_g + gA + 96 * DM + (k0));             \
        a0l = *(const bf16x8*)(Al_g + gA + (k0));                       \
        a1l = *(const bf16x8*)(Al_g + gA + 32 * DM + (k0));             \
        a2l = *(const bf16x8*)(Al_g + gA + 64 * DM + (k0));             \
        a3l = *(const bf16x8*)(Al_g + gA + 96 * DM + (k0));             \
        b0h = *(const bf16x8*)(Bsh + gB + (k0));                        \
        b1h = *(const bf16x8*)(Bsh + gB + 32 * 512 + (k0));             \
        b0l = *(const bf16x8*)(Bsl + gB + (k0));                        \
        b1l = *(const bf16x8*)(Bsl + gB + 32 * 512 + (k0));

    f32x4 acc[2][4];
    #pragma unroll
    for (int i = 0; i < 2; ++i)
        #pragma unroll
        for (int j = 0; j < 4; ++j)
            acc[i][j] = (f32x4){0.f, 0.f, 0.f, 0.f};

    GLOAD(0);

    for (int kt = 0; kt < 8; ++kt) {
        __syncthreads();
        *(bf16x8*)&Ah[r_a][wcol]      = a0h;
        *(bf16x8*)&Ah[r_a + 32][wcol] = a1h;
        *(bf16x8*)&Ah[r_a + 64][wcol] = a2h;
        *(bf16x8*)&Ah[r_a + 96][wcol] = a3h;
        *(bf16x8*)&Al[r_a][wcol]      = a0l;
        *(bf16x8*)&Al[r_a + 32][wcol] = a1l;
        *(bf16x8*)&Al[r_a + 64][wcol] = a2l;
        *(bf16x8*)&Al[r_a + 96][wcol] = a3l;
        *(bf16x8*)&Bh[r_a][wcol]      = b0h;
        *(bf16x8*)&Bh[r_a + 32][wcol] = b1h;
        *(bf16x8*)&Bl[r_a][wcol]      = b0l;
        *(bf16x8*)&Bl[r_a + 32][wcol] = b1l;
        __syncthreads();
        if (kt < 7) { GLOAD((kt + 1) * 64); }

        #pragma unroll
        for (int kk = 0; kk < 2; ++kk) {
            const int fc = (kk * 32 + lg * 8) ^ ((ln & 7) << 3);
            bf16x8 ah[2], al[2], bh2[4], bl2[4];
            #pragma unroll
            for (int ti = 0; ti < 2; ++ti) {
                ah[ti] = *(const bf16x8*)&Ah[w * 32 + ti * 16 + ln][fc];
                al[ti] = *(const bf16x8*)&Al[w * 32 + ti * 16 + ln][fc];
            }
            #pragma unroll
            for (int nj = 0; nj < 4; ++nj) {
                bh2[nj] = *(const bf16x8*)&Bh[nj * 16 + ln][fc];
                bl2[nj] = *(const bf16x8*)&Bl[nj * 16 + ln][fc];
            }
            #pragma unroll
            for (int ti = 0; ti < 2; ++ti)
                #pragma unroll
                for (int nj = 0; nj < 4; ++nj) {
                    acc[ti][nj] = MFMA(ah[ti], bh2[nj], acc[ti][nj]);
                    acc[ti][nj] = MFMA(ah[ti], bl2[nj], acc[ti][nj]);
                    acc[ti][nj] = MFMA(al[ti], bh2[nj], acc[ti][nj]);
                }
        }
    }
    #undef GLOAD

    const float qscale = (mode == 0 && y < 8) ? 0.125f : 1.0f;
    #pragma unroll
    for (int ti = 0; ti < 2; ++ti)
        #pragma unroll
        for (int nj = 0; nj < 4; ++nj)
            #pragma unroll
            for (int r = 0; r < 4; ++r) {
                float val = acc[ti][nj][r] * qscale;
                int t = r0 + w * 32 + ti * 16 + lg * 4 + r;
                int n = nj * 16 + ln;
                if (mode == 0) {
                    int bh = (t >> 12) * NH + (y & 7);
                    size_t off = ((size_t)bh * TSEQ + (t & (TSEQ - 1))) * HS + n;
                    u16 hb = f2bf(val);
                    u16 lb = f2bf(val - bf2f(hb));
                    if (y < 8) { O0h[off] = hb; O0l[off] = lb; }
                    else       { O1h[off] = hb; O1l[off] = lb; }
                } else {
                    Of[(size_t)t * DM + y * 64 + n] = val;
                }
            }
}

// ---------------------------------------------------------------------------
// V transpose: Vn[bh][u][s] -> Vt[bh][s][u] (hi/lo). LDS-tiled. (R7, proven)
// ---------------------------------------------------------------------------
__global__ __launch_bounds__(256) void transpose_v(
    const u16* __restrict__ Vnh, const u16* __restrict__ Vnl,
    u16* __restrict__ Vth, u16* __restrict__ Vtl)
{
    __shared__ u16 T[64][72];

    const int tid = threadIdx.x;
    const int bh = blockIdx.x >> 6;
    const int u0 = (blockIdx.x & 63) * 64;
    const size_t base = (size_t)bh * TSEQ * HS;

    const int lu = tid >> 2;
    const int s8 = (tid & 3) * 16;
    const int so = tid >> 2;
    const int u8 = (tid & 3) * 16;

    #pragma unroll
    for (int plane = 0; plane < 2; ++plane) {
        const u16* src = plane ? Vnl : Vnh;
        u16* dst = plane ? Vtl : Vth;
        size_t goff = base + (size_t)(u0 + lu) * HS + s8;
        bf16x8 v0 = *(const bf16x8*)(src + goff);
        bf16x8 v1 = *(const bf16x8*)(src + goff + 8);
        *(bf16x8*)&T[lu][s8]     = v0;
        *(bf16x8*)&T[lu][s8 + 8] = v1;
        __syncthreads();
        union { u16 a[16]; bf16x8 v[2]; } out;
        #pragma unroll
        for (int e = 0; e < 16; ++e)
            out.a[e] = T[u8 + e][so];
        size_t doff = base + (size_t)so * TSEQ + u0 + u8;
        *(bf16x8*)(dst + doff)     = out.v[0];
        *(bf16x8*)(dst + doff + 8) = out.v[1];
        __syncthreads();
    }
}

// ---------------------------------------------------------------------------
// Banded flash attention v3 = R6's proven attn_mfma with ONE change:
// the Vt tile is staged from the pre-transposed global array (pure swizzled
// b128 copies) instead of the in-kernel staggered scalar transpose.
// Everything else (scores, softmax, packed-u32 P + perm unpack, epilogue)
// is identical to the R6 kernel that passed at 93.6 us.
// ---------------------------------------------------------------------------
__global__ __launch_bounds__(256) void attn_v3(
    const u16* __restrict__ Qh_g, const u16* __restrict__ Ql_g,
    const u16* __restrict__ Vnh_g, const u16* __restrict__ Vnl_g,
    const u16* __restrict__ Vth_g, const u16* __restrict__ Vtl_g,
    u16* __restrict__ Ch, u16* __restrict__ Cl)
{
    __shared__ u16 Vn_h[64][64], Vn_l[64][64];   // [u][s^((u&7)<<3)]
    __shared__ u16 Vt_h[64][64], Vt_l[64][64];   // [s][u^((s&7)<<3)]
    __shared__ unsigned Ps[128][32];             // [t][(u&31)^((t&7)<<2)]

    const int tid = threadIdx.x;
    const int w = tid >> 6, lane = tid & 63;
    const int lg = lane >> 4, ln = lane & 15;
    const int ttile = blockIdx.x & 31;
    const int bh = blockIdx.x >> 5;
    const int t0 = ttile * 128;
    const size_t base = (size_t)bh * TSEQ * HS;
    const u16* Qph = Qh_g + base;
    const u16* Qpl = Ql_g + base;
    const u16* Vph = Vnh_g + base;
    const u16* Vpl = Vnl_g + base;
    const u16* Vth = Vth_g + base;   // [s][u], row stride TSEQ
    const u16* Vtl = Vtl_g + base;

    bf16x8 qh[2][2], ql[2][2];
    #pragma unroll
    for (int ti = 0; ti < 2; ++ti)
        #pragma unroll
        for (int kk = 0; kk < 2; ++kk) {
            int trow = t0 + w * 32 + ti * 16 + ln;
            size_t off = (size_t)trow * HS + kk * 32 + lg * 8;
            qh[ti][kk] = *(const bf16x8*)(Qph + off);
            ql[ti][kk] = *(const bf16x8*)(Qpl + off);
        }

    f32x4 o[2][4];
    float m[2][4], lsum[2][4];
    #pragma unroll
    for (int ti = 0; ti < 2; ++ti)
        #pragma unroll
        for (int j = 0; j < 4; ++j) {
            o[ti][j] = (f32x4){0.f, 0.f, 0.f, 0.f};
            m[ti][j] = -1e30f;
            lsum[ti][j] = 0.f;
        }

    int u_lo = t0 - CTX; if (u_lo < 0) u_lo = 0;
    int u_hi = t0 + 128 + CTX; if (u_hi > TSEQ) u_hi = TSEQ;

    // staging geometry: each thread covers rows sr and sr+32 of each plane
    const int sr = tid >> 3;            // 0..31
    const int c8 = (tid & 7) * 8;
    const int wcA = c8 ^ ((sr & 7) << 3);   // (sr+32)&7 == sr&7

    bf16x8 vn0h, vn1h, vn0l, vn1l, vt0h, vt1h, vt0l, vt1l;   // named regs
    #define VL(u0v)                                                             \
        vn0h = *(const bf16x8*)(Vph + (size_t)((u0v) + sr) * HS + c8);          \
        vn1h = *(const bf16x8*)(Vph + (size_t)((u0v) + sr + 32) * HS + c8);     \
        vn0l = *(const bf16x8*)(Vpl + (size_t)((u0v) + sr) * HS + c8);          \
        vn1l = *(const bf16x8*)(Vpl + (size_t)((u0v) + sr + 32) * HS + c8);     \
        vt0h = *(const bf16x8*)(Vth + (size_t)sr * TSEQ + (u0v) + c8);          \
        vt1h = *(const bf16x8*)(Vth + (size_t)(sr + 32) * TSEQ + (u0v) + c8);   \
        vt0l = *(const bf16x8*)(Vtl + (size_t)sr * TSEQ + (u0v) + c8);          \
        vt1l = *(const bf16x8*)(Vtl + (size_t)(sr + 32) * TSEQ + (u0v) + c8);

    VL(u_lo);

    for (int u0 = u_lo; u0 < u_hi; u0 += 64) {
        __syncthreads();
        *(bf16x8*)&Vn_h[sr][wcA]      = vn0h;
        *(bf16x8*)&Vn_h[sr + 32][wcA] = vn1h;
        *(bf16x8*)&Vn_l[sr][wcA]      = vn0l;
        *(bf16x8*)&Vn_l[sr + 32][wcA] = vn1l;
        *(bf16x8*)&Vt_h[sr][wcA]      = vt0h;
        *(bf16x8*)&Vt_h[sr + 32][wcA] = vt1h;
        *(bf16x8*)&Vt_l[sr][wcA]      = vt0l;
        *(bf16x8*)&Vt_l[sr + 32][wcA] = vt1l;
        __syncthreads();
        if (u0 + 64 < u_hi) { VL(u0 + 64); }

        // ---- scores: S[t][u] = sum_s Q[t][s] V[u][s]
        f32x4 s[2][4];
        #pragma unroll
        for (int ti = 0; ti < 2; ++ti)
            #pragma unroll
            for (int j = 0; j < 4; ++j)
                s[ti][j] = (f32x4){0.f, 0.f, 0.f, 0.f};

        #pragma unroll
        for (int kk = 0; kk < 2; ++kk) {
            const int fc = (kk * 32 + lg * 8) ^ ((ln & 7) << 3);
            bf16x8 vh[4], vl[4];
            #pragma unroll
            for (int uj = 0; uj < 4; ++uj) {
                vh[uj] = *(const bf16x8*)&Vn_h[uj * 16 + ln][fc];
                vl[uj] = *(const bf16x8*)&Vn_l[uj * 16 + ln][fc];
            }
            #pragma unroll
            for (int ti = 0; ti < 2; ++ti)
                #pragma unroll
                for (int uj = 0; uj < 4; ++uj) {
                    s[ti][uj] = MFMA(qh[ti][kk], vh[uj], s[ti][uj]);
                    s[ti][uj] = MFMA(qh[ti][kk], vl[uj], s[ti][uj]);
                    s[ti][uj] = MFMA(ql[ti][kk], vh[uj], s[ti][uj]);
                }
        }

        // ---- band mask
        bool needmask = ((t0 + 127 - u0) > CTX) || ((u0 + 63 - t0) > CTX);
        if (needmask) {
            #pragma unroll
            for (int ti = 0; ti < 2; ++ti)
                #pragma unroll
                for (int uj = 0; uj < 4; ++uj)
                    #pragma unroll
                    for (int r = 0; r < 4; ++r) {
                        int t = t0 + w * 32 + ti * 16 + lg * 4 + r;
                        int u = u0 + uj * 16 + ln;
                        int d = t - u; if (d < 0) d = -d;
                        if (d > CTX) s[ti][uj][r] = -1e30f;
                    }
        }

        // ---- online softmax per row
        float scl[2][4];
        #pragma unroll
        for (int ti = 0; ti < 2; ++ti)
            #pragma unroll
            for (int r = 0; r < 4; ++r) {
                float rm = fmaxf(fmaxf(s[ti][0][r], s[ti][1][r]),
                                 fmaxf(s[ti][2][r], s[ti][3][r]));
                rm = fmaxf(rm, __shfl_xor(rm, 1));
                rm = fmaxf(rm, __shfl_xor(rm, 2));
                rm = fmaxf(rm, __shfl_xor(rm, 4));
                rm = fmaxf(rm, __shfl_xor(rm, 8));
                float mn = fmaxf(m[ti][r], rm);
                float sc2 = __expf(m[ti][r] - mn);
                m[ti][r] = mn;
                scl[ti][r] = sc2;
                float rs = 0.f;
                #pragma unroll
                for (int uj = 0; uj < 4; ++uj) {
                    float p = __expf(s[ti][uj][r] - mn);
                    s[ti][uj][r] = p;
                    rs += p;
                }
                rs += __shfl_xor(rs, 1);
                rs += __shfl_xor(rs, 2);
                rs += __shfl_xor(rs, 4);
                rs += __shfl_xor(rs, 8);
                lsum[ti][r] = lsum[ti][r] * sc2 + rs;
            }

        // ---- rescale running O
        #pragma unroll
        for (int ti = 0; ti < 2; ++ti)
            #pragma unroll
            for (int sj = 0; sj < 4; ++sj)
                #pragma unroll
                for (int r = 0; r < 4; ++r)
                    o[ti][sj][r] *= scl[ti][r];

        // ---- PV in two u-halves; P half-strip same-wave LDS roundtrip
        #pragma unroll
        for (int kk = 0; kk < 2; ++kk) {
            #pragma unroll
            for (int ti = 0; ti < 2; ++ti)
                #pragma unroll
                for (int u2 = 0; u2 < 2; ++u2) {
                    int uj = kk * 2 + u2;
                    #pragma unroll
                    for (int r = 0; r < 4; ++r) {
                        int trow = w * 32 + ti * 16 + lg * 4 + r;
                        int ucol = (u2 * 16 + ln) ^ ((trow & 7) << 2);
                        Ps[trow][ucol] = pack_split(s[ti][uj][r]);
                    }
                }

            bf16x8 ph[2], pl[2], vth4[4], vtl4[4];
            #pragma unroll
            for (int ti = 0; ti < 2; ++ti) {
                int prow = w * 32 + ti * 16 + ln;
                int sw = (ln & 7) << 2;
                uint4 q0 = *(const uint4*)&Ps[prow][(lg * 8) ^ sw];
                uint4 q1 = *(const uint4*)&Ps[prow][(lg * 8 + 4) ^ sw];
                union { unsigned u[4]; bf16x8 v; } H, L;
                H.u[0] = __builtin_amdgcn_perm(q0.y, q0.x, 0x05040100u);
                H.u[1] = __builtin_amdgcn_perm(q0.w, q0.z, 0x05040100u);
                H.u[2] = __builtin_amdgcn_perm(q1.y, q1.x, 0x05040100u);
                H.u[3] = __builtin_amdgcn_perm(q1.w, q1.z, 0x05040100u);
                L.u[0] = __builtin_amdgcn_perm(q0.y, q0.x, 0x07060302u);
                L.u[1] = __builtin_amdgcn_perm(q0.w, q0.z, 0x07060302u);
                L.u[2] = __builtin_amdgcn_perm(q1.y, q1.x, 0x07060302u);
                L.u[3] = __builtin_amdgcn_perm(q1.w, q1.z, 0x07060302u);
                ph[ti] = H.v;
                pl[ti] = L.v;
            }
            const int fct = (kk * 32 + lg * 8) ^ ((ln & 7) << 3);
            #pragma unroll
            for (int sj = 0; sj < 4; ++sj) {
                vth4[sj] = *(const bf16x8*)&Vt_h[sj * 16 + ln][fct];
                vtl4[sj] = *(const bf16x8*)&Vt_l[sj * 16 + ln][fct];
            }
            #pragma unroll
            for (int ti = 0; ti < 2; ++ti)
                #pragma unroll
                for (int sj = 0; sj < 4; ++sj) {
                    o[ti][sj] = MFMA(ph[ti], vth4[sj], o[ti][sj]);
                    o[ti][sj] = MFMA(ph[ti], vtl4[sj], o[ti][sj]);
                    o[ti][sj] = MFMA(pl[ti], vth4[sj], o[ti][sj]);
                }
        }
    }
    #undef VL

    // ---- epilogue: C split bf16, layout [b][t][h*64+s]
    const int b = bh >> 3, h = bh & 7;
    #pragma unroll
    for (int ti = 0; ti < 2; ++ti)
        #pragma unroll
        for (int r = 0; r < 4; ++r) {
            float inv = 1.f / lsum[ti][r];
            int t = t0 + w * 32 + ti * 16 + lg * 4 + r;
            #pragma unroll
            for (int sj = 0; sj < 4; ++sj) {
                int ss = sj * 16 + ln;
                float val = o[ti][sj][r] * inv;
                size_t off = ((size_t)(b * TSEQ + t)) * DM + h * HS + ss;
                u16 hb = f2bf(val);
                Ch[off] = hb;
                Cl[off] = f2bf(val - bf2f(hb));
            }
        }
}

// ---------------------------------------------------------------------------
extern "C" void kernel_launch(void* const* d_in, const int* in_sizes, int n_in,
                              void* d_out, int out_size, void* d_ws, size_t ws_size,
                              hipStream_t stream) {
    const float* X  = (const float*)d_in[0];
    const float* WQ = (const float*)d_in[1];
    const float* WV = (const float*)d_in[2];
    const float* WU = (const float*)d_in[3];
    float* out = (float*)d_out;

    const size_t SZ = 8388608;   // 8 MB region
    char* ws = (char*)d_ws;

    u16* Xh = (u16*)(ws);             // later reused as Ch
    u16* Xl = (u16*)(ws + SZ);        // later reused as Cl
    u16* Qh = (u16*)(ws + 2 * SZ);
    u16* Ql = (u16*)(ws + 3 * SZ);
    u16* Vh = (u16*)(ws + 4 * SZ);
    u16* Vl = (u16*)(ws + 5 * SZ);
    u16* Vth = (u16*)(ws + 6 * SZ);
    u16* Vtl = (u16*)(ws + 7 * SZ);
    char* wsw = ws + 8 * SZ;
    u16* WQt_h = (u16*)(wsw);
    u16* WQt_l = (u16*)(wsw + 524288);
    u16* WVt_h = (u16*)(wsw + 2 * 524288);
    u16* WVt_l = (u16*)(wsw + 3 * 524288);
    u16* WUt_h = (u16*)(wsw + 4 * 524288);
    u16* WUt_l = (u16*)(wsw + 5 * 524288);

    presplit_x<<<2048, 256, 0, stream>>>(X, Xh, Xl);
    presplit_w<<<3072, 256, 0, stream>>>(WQ, WV, WU, WQt_h, WQt_l,
                                         WVt_h, WVt_l, WUt_h, WUt_l);
    gemm_mfma<<<dim3(64, 16), 256, 0, stream>>>(
        Xh, Xl, WQt_h, WQt_l, WVt_h, WVt_l, Qh, Ql, Vh, Vl, nullptr, 0);
    transpose_v<<<1024, 256, 0, stream>>>(Vh, Vl, Vth, Vtl);
    attn_v3<<<512, 256, 0, stream>>>(Qh, Ql, Vh, Vl, Vth, Vtl, Xh, Xl);
    gemm_mfma<<<dim3(64, 8), 256, 0, stream>>>(
        Xh, Xl, WUt_h, WUt_l, nullptr, nullptr,
        nullptr, nullptr, nullptr, nullptr, out, 1);
}

// Round 11
// 121.706 us; speedup vs baseline: 1.4403x; 1.2457x over previous
//
#include <hip/hip_runtime.h>

#define TSEQ 4096
#define DM 512
#define NH 8
#define HS 64
#define CTX 256

typedef __attribute__((ext_vector_type(8))) short bf16x8;
typedef __attribute__((ext_vector_type(4))) float f32x4;
typedef unsigned short u16;
typedef unsigned long long ull;

__device__ __forceinline__ u16 f2bf(float x) {
    unsigned u = __float_as_uint(x);
    unsigned r = (u + 0x7fffu + ((u >> 16) & 1u)) >> 16;
    return (u16)r;
}
__device__ __forceinline__ float bf2f(u16 b) {
    return __uint_as_float(((unsigned)b) << 16);
}
// bf16(p) duplicated in both u16 halves — 1 instruction
__device__ __forceinline__ unsigned bf16dup(float p) {
    unsigned w;
    asm("v_cvt_pk_bf16_f32 %0, %1, %1" : "=v"(w) : "v"(p));
    return w;
}
__device__ __forceinline__ void split8(const float* v, bf16x8& h, bf16x8& l) {
    #pragma unroll
    for (int i = 0; i < 8; ++i) {
        u16 hb = f2bf(v[i]);
        float hf = bf2f(hb);
        u16 lb = f2bf(v[i] - hf);
        h[i] = (short)hb;
        l[i] = (short)lb;
    }
}

#define MFMA(a, b, c) __builtin_amdgcn_mfma_f32_16x16x32_bf16((a), (b), (c), 0, 0, 0)

// ---------------------------------------------------------------------------
__global__ __launch_bounds__(256) void presplit_x(
    const float* __restrict__ X, u16* __restrict__ Xh, u16* __restrict__ Xl)
{
    size_t idx = ((size_t)blockIdx.x * 256 + threadIdx.x) * 8;
    float4 p0 = *(const float4*)(X + idx);
    float4 p1 = *(const float4*)(X + idx + 4);
    float v[8] = {p0.x, p0.y, p0.z, p0.w, p1.x, p1.y, p1.z, p1.w};
    bf16x8 h, l;
    split8(v, h, l);
    *(bf16x8*)(Xh + idx) = h;
    *(bf16x8*)(Xl + idx) = l;
}

// ---------------------------------------------------------------------------
__global__ __launch_bounds__(256) void presplit_w(
    const float* __restrict__ WQ, const float* __restrict__ WV,
    const float* __restrict__ WU,
    u16* __restrict__ WQt_h, u16* __restrict__ WQt_l,
    u16* __restrict__ WVt_h, u16* __restrict__ WVt_l,
    u16* __restrict__ WUt_h, u16* __restrict__ WUt_l)
{
    int gidx = blockIdx.x * 256 + threadIdx.x;   // 0 .. 786431
    int a = gidx >> 18;                          // 0: WQ, 1: WV, 2: WU
    int r = gidx & 262143;
    float val;
    u16 *dh, *dl;
    int dst;
    if (a < 2) {
        int h = r >> 15, s = (r >> 9) & 63, d = r & 511;
        const float* W = (a == 0) ? WQ : WV;
        val = W[h * 32768 + d * 64 + s];
        dst = h * 32768 + s * 512 + d;
        dh = (a == 0) ? WQt_h : WVt_h;
        dl = (a == 0) ? WQt_l : WVt_l;
    } else {
        int n = r >> 9, k = r & 511;
        val = WU[k * 512 + n];
        dst = n * 512 + k;
        dh = WUt_h; dl = WUt_l;
    }
    u16 hb = f2bf(val);
    dh[dst] = hb;
    dl[dst] = f2bf(val - bf2f(hb));
}

// ---------------------------------------------------------------------------
// Split-bf16 MFMA GEMM (R6, proven). 128x64 tile, K=512, BK=64.
// ---------------------------------------------------------------------------
__global__ __launch_bounds__(256) void gemm_mfma(
    const u16* __restrict__ Ah_g, const u16* __restrict__ Al_g,
    const u16* __restrict__ B0h, const u16* __restrict__ B0l,
    const u16* __restrict__ B1h, const u16* __restrict__ B1l,
    u16* __restrict__ O0h, u16* __restrict__ O0l,
    u16* __restrict__ O1h, u16* __restrict__ O1l,
    float* __restrict__ Of,
    int mode)
{
    __shared__ u16 Ah[128][64], Al[128][64];
    __shared__ u16 Bh[64][64],  Bl[64][64];

    const int tid = threadIdx.x;
    const int w = tid >> 6, lane = tid & 63;
    const int lg = lane >> 4, ln = lane & 15;
    const int r0 = blockIdx.x * 128;
    const int y = blockIdx.y;

    const u16 *Bsh, *Bsl;
    if (mode == 0) {
        if (y < 8) { Bsh = B0h + (size_t)y * 32768; Bsl = B0l + (size_t)y * 32768; }
        else       { Bsh = B1h + (size_t)(y - 8) * 32768; Bsl = B1l + (size_t)(y - 8) * 32768; }
    } else {
        Bsh = B0h + (size_t)y * 64 * 512;
        Bsl = B0l + (size_t)y * 64 * 512;
    }

    const int r_a = tid >> 3;
    const int kc  = tid & 7;
    const int wcol = (kc * 8) ^ ((r_a & 7) << 3);
    const size_t gA = (size_t)(r0 + r_a) * DM + kc * 8;
    const size_t gB = (size_t)r_a * 512 + kc * 8;

    bf16x8 a0h, a1h, a2h, a3h, a0l, a1l, a2l, a3l, b0h, b1h, b0l, b1l;

    #define GLOAD(k0)                                                   \
        a0h = *(const bf16x8*)(Ah_g + gA + (k0));                       \
        a1h = *(const bf16x8*)(Ah_g + gA + 32 * DM + (k0));             \
        a2h = *(const bf16x8*)(Ah_g + gA + 64 * DM + (k0));             \
        a3h = *(const bf16x8*)(Ah_g + gA + 96 * DM + (k0));             \
        a0l = *(const bf16x8*)(Al_g + gA + (k0));                       \
        a1l = *(const bf16x8*)(Al_g + gA + 32 * DM + (k0));             \
        a2l = *(const bf16x8*)(Al_g + gA + 64 * DM + (k0));             \
        a3l = *(const bf16x8*)(Al_g + gA + 96 * DM + (k0));             \
        b0h = *(const bf16x8*)(Bsh + gB + (k0));                        \
        b1h = *(const bf16x8*)(Bsh + gB + 32 * 512 + (k0));             \
        b0l = *(const bf16x8*)(Bsl + gB + (k0));                        \
        b1l = *(const bf16x8*)(Bsl + gB + 32 * 512 + (k0));

    f32x4 acc[2][4];
    #pragma unroll
    for (int i = 0; i < 2; ++i)
        #pragma unroll
        for (int j = 0; j < 4; ++j)
            acc[i][j] = (f32x4){0.f, 0.f, 0.f, 0.f};

    GLOAD(0);

    for (int kt = 0; kt < 8; ++kt) {
        __syncthreads();
        *(bf16x8*)&Ah[r_a][wcol]      = a0h;
        *(bf16x8*)&Ah[r_a + 32][wcol] = a1h;
        *(bf16x8*)&Ah[r_a + 64][wcol] = a2h;
        *(bf16x8*)&Ah[r_a + 96][wcol] = a3h;
        *(bf16x8*)&Al[r_a][wcol]      = a0l;
        *(bf16x8*)&Al[r_a + 32][wcol] = a1l;
        *(bf16x8*)&Al[r_a + 64][wcol] = a2l;
        *(bf16x8*)&Al[r_a + 96][wcol] = a3l;
        *(bf16x8*)&Bh[r_a][wcol]      = b0h;
        *(bf16x8*)&Bh[r_a + 32][wcol] = b1h;
        *(bf16x8*)&Bl[r_a][wcol]      = b0l;
        *(bf16x8*)&Bl[r_a + 32][wcol] = b1l;
        __syncthreads();
        if (kt < 7) { GLOAD((kt + 1) * 64); }

        #pragma unroll
        for (int kk = 0; kk < 2; ++kk) {
            const int fc = (kk * 32 + lg * 8) ^ ((ln & 7) << 3);
            bf16x8 ah[2], al[2], bh2[4], bl2[4];
            #pragma unroll
            for (int ti = 0; ti < 2; ++ti) {
                ah[ti] = *(const bf16x8*)&Ah[w * 32 + ti * 16 + ln][fc];
                al[ti] = *(const bf16x8*)&Al[w * 32 + ti * 16 + ln][fc];
            }
            #pragma unroll
            for (int nj = 0; nj < 4; ++nj) {
                bh2[nj] = *(const bf16x8*)&Bh[nj * 16 + ln][fc];
                bl2[nj] = *(const bf16x8*)&Bl[nj * 16 + ln][fc];
            }
            #pragma unroll
            for (int ti = 0; ti < 2; ++ti)
                #pragma unroll
                for (int nj = 0; nj < 4; ++nj) {
                    acc[ti][nj] = MFMA(ah[ti], bh2[nj], acc[ti][nj]);
                    acc[ti][nj] = MFMA(ah[ti], bl2[nj], acc[ti][nj]);
                    acc[ti][nj] = MFMA(al[ti], bh2[nj], acc[ti][nj]);
                }
        }
    }
    #undef GLOAD

    const float qscale = (mode == 0 && y < 8) ? 0.125f : 1.0f;
    #pragma unroll
    for (int ti = 0; ti < 2; ++ti)
        #pragma unroll
        for (int nj = 0; nj < 4; ++nj)
            #pragma unroll
            for (int r = 0; r < 4; ++r) {
                float val = acc[ti][nj][r] * qscale;
                int t = r0 + w * 32 + ti * 16 + lg * 4 + r;
                int n = nj * 16 + ln;
                if (mode == 0) {
                    int bh = (t >> 12) * NH + (y & 7);
                    size_t off = ((size_t)bh * TSEQ + (t & (TSEQ - 1))) * HS + n;
                    u16 hb = f2bf(val);
                    u16 lb = f2bf(val - bf2f(hb));
                    if (y < 8) { O0h[off] = hb; O0l[off] = lb; }
                    else       { O1h[off] = hb; O1l[off] = lb; }
                } else {
                    Of[(size_t)t * DM + y * 64 + n] = val;
                }
            }
}

// ---------------------------------------------------------------------------
// V transpose (hi plane only): Vn_h[bh][u][s] -> Vt_h[bh][s][u]. LDS-tiled.
// ---------------------------------------------------------------------------
__global__ __launch_bounds__(256) void transpose_v(
    const u16* __restrict__ Vnh, u16* __restrict__ Vth)
{
    __shared__ u16 T[64][72];

    const int tid = threadIdx.x;
    const int bh = blockIdx.x >> 6;
    const int u0 = (blockIdx.x & 63) * 64;
    const size_t base = (size_t)bh * TSEQ * HS;

    const int lu = tid >> 2;
    const int s8 = (tid & 3) * 16;
    const int so = tid >> 2;
    const int u8 = (tid & 3) * 16;

    size_t goff = base + (size_t)(u0 + lu) * HS + s8;
    bf16x8 v0 = *(const bf16x8*)(Vnh + goff);
    bf16x8 v1 = *(const bf16x8*)(Vnh + goff + 8);
    *(bf16x8*)&T[lu][s8]     = v0;
    *(bf16x8*)&T[lu][s8 + 8] = v1;
    __syncthreads();
    union { u16 a[16]; bf16x8 v[2]; } out;
    #pragma unroll
    for (int e = 0; e < 16; ++e)
        out.a[e] = T[u8 + e][so];
    size_t doff = base + (size_t)so * TSEQ + u0 + u8;
    *(bf16x8*)(Vth + doff)     = out.v[0];
    *(bf16x8*)(Vth + doff + 8) = out.v[1];
}

// ---------------------------------------------------------------------------
// Banded flash attention v4 = R9's attn_v3 with a PV precision diet:
// P stored as plain bf16 (cvt_pk dup into the SAME u32 strip — addressing
// bit-identical), lo-P and lo-V PV terms deleted. QK keeps full split.
// PV: 16 MFMA/chunk/wave (was 48). LDS 40 KB.
// ---------------------------------------------------------------------------
__global__ __launch_bounds__(256) void attn_v4(
    const u16* __restrict__ Qh_g, const u16* __restrict__ Ql_g,
    const u16* __restrict__ Vnh_g, const u16* __restrict__ Vnl_g,
    const u16* __restrict__ Vth_g,
    u16* __restrict__ Ch, u16* __restrict__ Cl)
{
    __shared__ u16 Vn_h[64][64], Vn_l[64][64];   // [u][s^((u&7)<<3)]
    __shared__ u16 Vt_h[64][64];                 // [s][u^((s&7)<<3)]
    __shared__ unsigned Ps[128][32];             // [t][(u&31)^((t&7)<<2)]

    const int tid = threadIdx.x;
    const int w = tid >> 6, lane = tid & 63;
    const int lg = lane >> 4, ln = lane & 15;
    const int ttile = blockIdx.x & 31;
    const int bh = blockIdx.x >> 5;
    const int t0 = ttile * 128;
    const size_t base = (size_t)bh * TSEQ * HS;
    const u16* Qph = Qh_g + base;
    const u16* Qpl = Ql_g + base;
    const u16* Vph = Vnh_g + base;
    const u16* Vpl = Vnl_g + base;
    const u16* Vth = Vth_g + base;   // [s][u], row stride TSEQ

    bf16x8 qh[2][2], ql[2][2];
    #pragma unroll
    for (int ti = 0; ti < 2; ++ti)
        #pragma unroll
        for (int kk = 0; kk < 2; ++kk) {
            int trow = t0 + w * 32 + ti * 16 + ln;
            size_t off = (size_t)trow * HS + kk * 32 + lg * 8;
            qh[ti][kk] = *(const bf16x8*)(Qph + off);
            ql[ti][kk] = *(const bf16x8*)(Qpl + off);
        }

    f32x4 o[2][4];
    float m[2][4], lsum[2][4];
    #pragma unroll
    for (int ti = 0; ti < 2; ++ti)
        #pragma unroll
        for (int j = 0; j < 4; ++j) {
            o[ti][j] = (f32x4){0.f, 0.f, 0.f, 0.f};
            m[ti][j] = -1e30f;
            lsum[ti][j] = 0.f;
        }

    int u_lo = t0 - CTX; if (u_lo < 0) u_lo = 0;
    int u_hi = t0 + 128 + CTX; if (u_hi > TSEQ) u_hi = TSEQ;

    // staging geometry: each thread covers rows sr and sr+32 of each plane
    const int sr = tid >> 3;            // 0..31
    const int c8 = (tid & 7) * 8;
    const int wcA = c8 ^ ((sr & 7) << 3);

    bf16x8 vn0h, vn1h, vn0l, vn1l, vt0h, vt1h;   // named regs
    #define VL(u0v)                                                             \
        vn0h = *(const bf16x8*)(Vph + (size_t)((u0v) + sr) * HS + c8);          \
        vn1h = *(const bf16x8*)(Vph + (size_t)((u0v) + sr + 32) * HS + c8);     \
        vn0l = *(const bf16x8*)(Vpl + (size_t)((u0v) + sr) * HS + c8);          \
        vn1l = *(const bf16x8*)(Vpl + (size_t)((u0v) + sr + 32) * HS + c8);     \
        vt0h = *(const bf16x8*)(Vth + (size_t)sr * TSEQ + (u0v) + c8);          \
        vt1h = *(const bf16x8*)(Vth + (size_t)(sr + 32) * TSEQ + (u0v) + c8);

    VL(u_lo);

    for (int u0 = u_lo; u0 < u_hi; u0 += 64) {
        __syncthreads();
        *(bf16x8*)&Vn_h[sr][wcA]      = vn0h;
        *(bf16x8*)&Vn_h[sr + 32][wcA] = vn1h;
        *(bf16x8*)&Vn_l[sr][wcA]      = vn0l;
        *(bf16x8*)&Vn_l[sr + 32][wcA] = vn1l;
        *(bf16x8*)&Vt_h[sr][wcA]      = vt0h;
        *(bf16x8*)&Vt_h[sr + 32][wcA] = vt1h;
        __syncthreads();
        if (u0 + 64 < u_hi) { VL(u0 + 64); }

        // ---- scores: S[t][u] = sum_s Q[t][s] V[u][s]  (full split precision)
        f32x4 s[2][4];
        #pragma unroll
        for (int ti = 0; ti < 2; ++ti)
            #pragma unroll
            for (int j = 0; j < 4; ++j)
                s[ti][j] = (f32x4){0.f, 0.f, 0.f, 0.f};

        #pragma unroll
        for (int kk = 0; kk < 2; ++kk) {
            const int fc = (kk * 32 + lg * 8) ^ ((ln & 7) << 3);
            bf16x8 vh[4], vl[4];
            #pragma unroll
            for (int uj = 0; uj < 4; ++uj) {
                vh[uj] = *(const bf16x8*)&Vn_h[uj * 16 + ln][fc];
                vl[uj] = *(const bf16x8*)&Vn_l[uj * 16 + ln][fc];
            }
            #pragma unroll
            for (int ti = 0; ti < 2; ++ti)
                #pragma unroll
                for (int uj = 0; uj < 4; ++uj) {
                    s[ti][uj] = MFMA(qh[ti][kk], vh[uj], s[ti][uj]);
                    s[ti][uj] = MFMA(qh[ti][kk], vl[uj], s[ti][uj]);
                    s[ti][uj] = MFMA(ql[ti][kk], vh[uj], s[ti][uj]);
                }
        }

        // ---- band mask
        bool needmask = ((t0 + 127 - u0) > CTX) || ((u0 + 63 - t0) > CTX);
        if (needmask) {
            #pragma unroll
            for (int ti = 0; ti < 2; ++ti)
                #pragma unroll
                for (int uj = 0; uj < 4; ++uj)
                    #pragma unroll
                    for (int r = 0; r < 4; ++r) {
                        int t = t0 + w * 32 + ti * 16 + lg * 4 + r;
                        int u = u0 + uj * 16 + ln;
                        int d = t - u; if (d < 0) d = -d;
                        if (d > CTX) s[ti][uj][r] = -1e30f;
                    }
        }

        // ---- online softmax per row
        float scl[2][4];
        #pragma unroll
        for (int ti = 0; ti < 2; ++ti)
            #pragma unroll
            for (int r = 0; r < 4; ++r) {
                float rm = fmaxf(fmaxf(s[ti][0][r], s[ti][1][r]),
                                 fmaxf(s[ti][2][r], s[ti][3][r]));
                rm = fmaxf(rm, __shfl_xor(rm, 1));
                rm = fmaxf(rm, __shfl_xor(rm, 2));
                rm = fmaxf(rm, __shfl_xor(rm, 4));
                rm = fmaxf(rm, __shfl_xor(rm, 8));
                float mn = fmaxf(m[ti][r], rm);
                float sc2 = __expf(m[ti][r] - mn);
                m[ti][r] = mn;
                scl[ti][r] = sc2;
                float rs = 0.f;
                #pragma unroll
                for (int uj = 0; uj < 4; ++uj) {
                    float p = __expf(s[ti][uj][r] - mn);
                    s[ti][uj][r] = p;
                    rs += p;
                }
                rs += __shfl_xor(rs, 1);
                rs += __shfl_xor(rs, 2);
                rs += __shfl_xor(rs, 4);
                rs += __shfl_xor(rs, 8);
                lsum[ti][r] = lsum[ti][r] * sc2 + rs;
            }

        // ---- rescale running O
        #pragma unroll
        for (int ti = 0; ti < 2; ++ti)
            #pragma unroll
            for (int sj = 0; sj < 4; ++sj)
                #pragma unroll
                for (int r = 0; r < 4; ++r)
                    o[ti][sj][r] *= scl[ti][r];

        // ---- PV in two u-halves; P bf16 (dup'd halves) same strip as R9
        #pragma unroll
        for (int kk = 0; kk < 2; ++kk) {
            #pragma unroll
            for (int ti = 0; ti < 2; ++ti)
                #pragma unroll
                for (int u2 = 0; u2 < 2; ++u2) {
                    int uj = kk * 2 + u2;
                    #pragma unroll
                    for (int r = 0; r < 4; ++r) {
                        int trow = w * 32 + ti * 16 + lg * 4 + r;
                        int ucol = (u2 * 16 + ln) ^ ((trow & 7) << 2);
                        Ps[trow][ucol] = bf16dup(s[ti][uj][r]);
                    }
                }

            bf16x8 ph[2], vth4[4];
            #pragma unroll
            for (int ti = 0; ti < 2; ++ti) {
                int prow = w * 32 + ti * 16 + ln;
                int sw = (ln & 7) << 2;
                uint4 q0 = *(const uint4*)&Ps[prow][(lg * 8) ^ sw];
                uint4 q1 = *(const uint4*)&Ps[prow][(lg * 8 + 4) ^ sw];
                union { unsigned u[4]; bf16x8 v; } H;
                H.u[0] = __builtin_amdgcn_perm(q0.y, q0.x, 0x05040100u);
                H.u[1] = __builtin_amdgcn_perm(q0.w, q0.z, 0x05040100u);
                H.u[2] = __builtin_amdgcn_perm(q1.y, q1.x, 0x05040100u);
                H.u[3] = __builtin_amdgcn_perm(q1.w, q1.z, 0x05040100u);
                ph[ti] = H.v;
            }
            const int fct = (kk * 32 + lg * 8) ^ ((ln & 7) << 3);
            #pragma unroll
            for (int sj = 0; sj < 4; ++sj)
                vth4[sj] = *(const bf16x8*)&Vt_h[sj * 16 + ln][fct];
            #pragma unroll
            for (int ti = 0; ti < 2; ++ti)
                #pragma unroll
                for (int sj = 0; sj < 4; ++sj)
                    o[ti][sj] = MFMA(ph[ti], vth4[sj], o[ti][sj]);
        }
    }
    #undef VL

    // ---- epilogue: C split bf16, layout [b][t][h*64+s]
    const int b = bh >> 3, h = bh & 7;
    #pragma unroll
    for (int ti = 0; ti < 2; ++ti)
        #pragma unroll
        for (int r = 0; r < 4; ++r) {
            float inv = 1.f / lsum[ti][r];
            int t = t0 + w * 32 + ti * 16 + lg * 4 + r;
            #pragma unroll
            for (int sj = 0; sj < 4; ++sj) {
                int ss = sj * 16 + ln;
                float val = o[ti][sj][r] * inv;
                size_t off = ((size_t)(b * TSEQ + t)) * DM + h * HS + ss;
                u16 hb = f2bf(val);
                Ch[off] = hb;
                Cl[off] = f2bf(val - bf2f(hb));
            }
        }
}

// ---------------------------------------------------------------------------
extern "C" void kernel_launch(void* const* d_in, const int* in_sizes, int n_in,
                              void* d_out, int out_size, void* d_ws, size_t ws_size,
                              hipStream_t stream) {
    const float* X  = (const float*)d_in[0];
    const float* WQ = (const float*)d_in[1];
    const float* WV = (const float*)d_in[2];
    const float* WU = (const float*)d_in[3];
    float* out = (float*)d_out;

    const size_t SZ = 8388608;   // 8 MB region
    char* ws = (char*)d_ws;

    u16* Xh = (u16*)(ws);             // later reused as Ch
    u16* Xl = (u16*)(ws + SZ);        // later reused as Cl
    u16* Qh = (u16*)(ws + 2 * SZ);
    u16* Ql = (u16*)(ws + 3 * SZ);
    u16* Vh = (u16*)(ws + 4 * SZ);
    u16* Vl = (u16*)(ws + 5 * SZ);
    u16* Vth = (u16*)(ws + 6 * SZ);
    char* wsw = ws + 8 * SZ;
    u16* WQt_h = (u16*)(wsw);
    u16* WQt_l = (u16*)(wsw + 524288);
    u16* WVt_h = (u16*)(wsw + 2 * 524288);
    u16* WVt_l = (u16*)(wsw + 3 * 524288);
    u16* WUt_h = (u16*)(wsw + 4 * 524288);
    u16* WUt_l = (u16*)(wsw + 5 * 524288);

    presplit_x<<<2048, 256, 0, stream>>>(X, Xh, Xl);
    presplit_w<<<3072, 256, 0, stream>>>(WQ, WV, WU, WQt_h, WQt_l,
                                         WVt_h, WVt_l, WUt_h, WUt_l);
    gemm_mfma<<<dim3(64, 16), 256, 0, stream>>>(
        Xh, Xl, WQt_h, WQt_l, WVt_h, WVt_l, Qh, Ql, Vh, Vl, nullptr, 0);
    transpose_v<<<1024, 256, 0, stream>>>(Vh, Vth);
    attn_v4<<<512, 256, 0, stream>>>(Qh, Ql, Vh, Vl, Vth, Xh, Xl);
    gemm_mfma<<<dim3(64, 8), 256, 0, stream>>>(
        Xh, Xl, WUt_h, WUt_l, nullptr, nullptr,
        nullptr, nullptr, nullptr, nullptr, out, 1);
}

// Round 14
// 117.235 us; speedup vs baseline: 1.4952x; 1.0381x over previous
//
#include <hip/hip_runtime.h>

#define TSEQ 4096
#define DM 512
#define NH 8
#define HS 64
#define CTX 256

typedef __attribute__((ext_vector_type(8))) short bf16x8;
typedef __attribute__((ext_vector_type(4))) float f32x4;
typedef unsigned short u16;
typedef unsigned long long ull;

__device__ __forceinline__ u16 f2bf(float x) {
    unsigned u = __float_as_uint(x);
    unsigned r = (u + 0x7fffu + ((u >> 16) & 1u)) >> 16;
    return (u16)r;
}
__device__ __forceinline__ float bf2f(u16 b) {
    return __uint_as_float(((unsigned)b) << 16);
}
// bf16(p) duplicated in both u16 halves — 1 instruction
__device__ __forceinline__ unsigned bf16dup(float p) {
    unsigned w;
    asm("v_cvt_pk_bf16_f32 %0, %1, %1" : "=v"(w) : "v"(p));
    return w;
}
// DPP row-rotate (16-lane row) — replaces ds_bpermute shfl for reductions
template<int CTRL>
__device__ __forceinline__ float dpp_ror(float x) {
    int xi = __float_as_int(x);
    return __int_as_float(__builtin_amdgcn_update_dpp(xi, xi, CTRL, 0xf, 0xf, false));
}
__device__ __forceinline__ float row16_max(float v) {
    v = fmaxf(v, dpp_ror<0x121>(v));
    v = fmaxf(v, dpp_ror<0x122>(v));
    v = fmaxf(v, dpp_ror<0x124>(v));
    v = fmaxf(v, dpp_ror<0x128>(v));
    return v;
}
__device__ __forceinline__ float row16_sum(float v) {
    v += dpp_ror<0x121>(v);
    v += dpp_ror<0x122>(v);
    v += dpp_ror<0x124>(v);
    v += dpp_ror<0x128>(v);
    return v;
}
__device__ __forceinline__ void split8(const float* v, bf16x8& h, bf16x8& l) {
    #pragma unroll
    for (int i = 0; i < 8; ++i) {
        u16 hb = f2bf(v[i]);
        float hf = bf2f(hb);
        u16 lb = f2bf(v[i] - hf);
        h[i] = (short)hb;
        l[i] = (short)lb;
    }
}

#define MFMA(a, b, c) __builtin_amdgcn_mfma_f32_16x16x32_bf16((a), (b), (c), 0, 0, 0)

// ---------------------------------------------------------------------------
__global__ __launch_bounds__(256) void presplit_x(
    const float* __restrict__ X, u16* __restrict__ Xh, u16* __restrict__ Xl)
{
    size_t idx = ((size_t)blockIdx.x * 256 + threadIdx.x) * 8;
    float4 p0 = *(const float4*)(X + idx);
    float4 p1 = *(const float4*)(X + idx + 4);
    float v[8] = {p0.x, p0.y, p0.z, p0.w, p1.x, p1.y, p1.z, p1.w};
    bf16x8 h, l;
    split8(v, h, l);
    *(bf16x8*)(Xh + idx) = h;
    *(bf16x8*)(Xl + idx) = l;
}

// ---------------------------------------------------------------------------
__global__ __launch_bounds__(256) void presplit_w(
    const float* __restrict__ WQ, const float* __restrict__ WV,
    const float* __restrict__ WU,
    u16* __restrict__ WQt_h, u16* __restrict__ WQt_l,
    u16* __restrict__ WVt_h, u16* __restrict__ WVt_l,
    u16* __restrict__ WUt_h, u16* __restrict__ WUt_l)
{
    int gidx = blockIdx.x * 256 + threadIdx.x;   // 0 .. 786431
    int a = gidx >> 18;                          // 0: WQ, 1: WV, 2: WU
    int r = gidx & 262143;
    float val;
    u16 *dh, *dl;
    int dst;
    if (a < 2) {
        int h = r >> 15, s = (r >> 9) & 63, d = r & 511;
        const float* W = (a == 0) ? WQ : WV;
        val = W[h * 32768 + d * 64 + s];
        dst = h * 32768 + s * 512 + d;
        dh = (a == 0) ? WQt_h : WVt_h;
        dl = (a == 0) ? WQt_l : WVt_l;
    } else {
        int n = r >> 9, k = r & 511;
        val = WU[k * 512 + n];
        dst = n * 512 + k;
        dh = WUt_h; dl = WUt_l;
    }
    u16 hb = f2bf(val);
    dh[dst] = hb;
    dl[dst] = f2bf(val - bf2f(hb));
}

// ---------------------------------------------------------------------------
// Split-bf16 MFMA GEMM (R6, proven). 128x64 tile, K=512, BK=64.
// Q output prescaled by log2(e)/8 (softmax runs in exp2 domain).
// V output: hi plane only (V-lo is no longer consumed anywhere).
// ---------------------------------------------------------------------------
__global__ __launch_bounds__(256) void gemm_mfma(
    const u16* __restrict__ Ah_g, const u16* __restrict__ Al_g,
    const u16* __restrict__ B0h, const u16* __restrict__ B0l,
    const u16* __restrict__ B1h, const u16* __restrict__ B1l,
    u16* __restrict__ O0h, u16* __restrict__ O0l,
    u16* __restrict__ O1h, u16* __restrict__ O1l,
    float* __restrict__ Of,
    int mode)
{
    __shared__ u16 Ah[128][64], Al[128][64];
    __shared__ u16 Bh[64][64],  Bl[64][64];

    const int tid = threadIdx.x;
    const int w = tid >> 6, lane = tid & 63;
    const int lg = lane >> 4, ln = lane & 15;
    const int r0 = blockIdx.x * 128;
    const int y = blockIdx.y;

    const u16 *Bsh, *Bsl;
    if (mode == 0) {
        if (y < 8) { Bsh = B0h + (size_t)y * 32768; Bsl = B0l + (size_t)y * 32768; }
        else       { Bsh = B1h + (size_t)(y - 8) * 32768; Bsl = B1l + (size_t)(y - 8) * 32768; }
    } else {
        Bsh = B0h + (size_t)y * 64 * 512;
        Bsl = B0l + (size_t)y * 64 * 512;
    }

    const int r_a = tid >> 3;
    const int kc  = tid & 7;
    const int wcol = (kc * 8) ^ ((r_a & 7) << 3);
    const size_t gA = (size_t)(r0 + r_a) * DM + kc * 8;
    const size_t gB = (size_t)r_a * 512 + kc * 8;

    bf16x8 a0h, a1h, a2h, a3h, a0l, a1l, a2l, a3l, b0h, b1h, b0l, b1l;

    #define GLOAD(k0)                                                   \
        a0h = *(const bf16x8*)(Ah_g + gA + (k0));                       \
        a1h = *(const bf16x8*)(Ah_g + gA + 32 * DM + (k0));             \
        a2h = *(const bf16x8*)(Ah_g + gA + 64 * DM + (k0));             \
        a3h = *(const bf16x8*)(Ah_g + gA + 96 * DM + (k0));             \
        a0l = *(const bf16x8*)(Al_g + gA + (k0));                       \
        a1l = *(const bf16x8*)(Al_g + gA + 32 * DM + (k0));             \
        a2l = *(const bf16x8*)(Al_g + gA + 64 * DM + (k0));             \
        a3l = *(const bf16x8*)(Al_g + gA + 96 * DM + (k0));             \
        b0h = *(const bf16x8*)(Bsh + gB + (k0));                        \
        b1h = *(const bf16x8*)(Bsh + gB + 32 * 512 + (k0));             \
        b0l = *(const bf16x8*)(Bsl + gB + (k0));                        \
        b1l = *(const bf16x8*)(Bsl + gB + 32 * 512 + (k0));

    f32x4 acc[2][4];
    #pragma unroll
    for (int i = 0; i < 2; ++i)
        #pragma unroll
        for (int j = 0; j < 4; ++j)
            acc[i][j] = (f32x4){0.f, 0.f, 0.f, 0.f};

    GLOAD(0);

    for (int kt = 0; kt < 8; ++kt) {
        __syncthreads();
        *(bf16x8*)&Ah[r_a][wcol]      = a0h;
        *(bf16x8*)&Ah[r_a + 32][wcol] = a1h;
        *(bf16x8*)&Ah[r_a + 64][wcol] = a2h;
        *(bf16x8*)&Ah[r_a + 96][wcol] = a3h;
        *(bf16x8*)&Al[r_a][wcol]      = a0l;
        *(bf16x8*)&Al[r_a + 32][wcol] = a1l;
        *(bf16x8*)&Al[r_a + 64][wcol] = a2l;
        *(bf16x8*)&Al[r_a + 96][wcol] = a3l;
        *(bf16x8*)&Bh[r_a][wcol]      = b0h;
        *(bf16x8*)&Bh[r_a + 32][wcol] = b1h;
        *(bf16x8*)&Bl[r_a][wcol]      = b0l;
        *(bf16x8*)&Bl[r_a + 32][wcol] = b1l;
        __syncthreads();
        if (kt < 7) { GLOAD((kt + 1) * 64); }

        #pragma unroll
        for (int kk = 0; kk < 2; ++kk) {
            const int fc = (kk * 32 + lg * 8) ^ ((ln & 7) << 3);
            bf16x8 ah[2], al[2], bh2[4], bl2[4];
            #pragma unroll
            for (int ti = 0; ti < 2; ++ti) {
                ah[ti] = *(const bf16x8*)&Ah[w * 32 + ti * 16 + ln][fc];
                al[ti] = *(const bf16x8*)&Al[w * 32 + ti * 16 + ln][fc];
            }
            #pragma unroll
            for (int nj = 0; nj < 4; ++nj) {
                bh2[nj] = *(const bf16x8*)&Bh[nj * 16 + ln][fc];
                bl2[nj] = *(const bf16x8*)&Bl[nj * 16 + ln][fc];
            }
            #pragma unroll
            for (int ti = 0; ti < 2; ++ti)
                #pragma unroll
                for (int nj = 0; nj < 4; ++nj) {
                    acc[ti][nj] = MFMA(ah[ti], bh2[nj], acc[ti][nj]);
                    acc[ti][nj] = MFMA(ah[ti], bl2[nj], acc[ti][nj]);
                    acc[ti][nj] = MFMA(al[ti], bh2[nj], acc[ti][nj]);
                }
        }
    }
    #undef GLOAD

    // Q prescale includes log2(e) so softmax can use exp2
    const float qscale = (mode == 0 && y < 8) ? 0.18033688f : 1.0f;
    #pragma unroll
    for (int ti = 0; ti < 2; ++ti)
        #pragma unroll
        for (int nj = 0; nj < 4; ++nj)
            #pragma unroll
            for (int r = 0; r < 4; ++r) {
                float val = acc[ti][nj][r] * qscale;
                int t = r0 + w * 32 + ti * 16 + lg * 4 + r;
                int n = nj * 16 + ln;
                if (mode == 0) {
                    int bh = (t >> 12) * NH + (y & 7);
                    size_t off = ((size_t)bh * TSEQ + (t & (TSEQ - 1))) * HS + n;
                    u16 hb = f2bf(val);
                    if (y < 8) {
                        O0h[off] = hb;
                        O0l[off] = f2bf(val - bf2f(hb));
                    } else {
                        O1h[off] = hb;   // V lo plane not needed
                    }
                } else {
                    Of[(size_t)t * DM + y * 64 + n] = val;
                }
            }
}

// ---------------------------------------------------------------------------
// V transpose (hi plane only): Vn_h[bh][u][s] -> Vt_h[bh][s][u]. LDS-tiled.
// ---------------------------------------------------------------------------
__global__ __launch_bounds__(256) void transpose_v(
    const u16* __restrict__ Vnh, u16* __restrict__ Vth)
{
    __shared__ u16 T[64][72];

    const int tid = threadIdx.x;
    const int bh = blockIdx.x >> 6;
    const int u0 = (blockIdx.x & 63) * 64;
    const size_t base = (size_t)bh * TSEQ * HS;

    const int lu = tid >> 2;
    const int s8 = (tid & 3) * 16;
    const int so = tid >> 2;
    const int u8 = (tid & 3) * 16;

    size_t goff = base + (size_t)(u0 + lu) * HS + s8;
    bf16x8 v0 = *(const bf16x8*)(Vnh + goff);
    bf16x8 v1 = *(const bf16x8*)(Vnh + goff + 8);
    *(bf16x8*)&T[lu][s8]     = v0;
    *(bf16x8*)&T[lu][s8 + 8] = v1;
    __syncthreads();
    union { u16 a[16]; bf16x8 v[2]; } out;
    #pragma unroll
    for (int e = 0; e < 16; ++e)
        out.a[e] = T[u8 + e][so];
    size_t doff = base + (size_t)so * TSEQ + u0 + u8;
    *(bf16x8*)(Vth + doff)     = out.v[0];
    *(bf16x8*)(Vth + doff + 8) = out.v[1];
}

// ---------------------------------------------------------------------------
// Banded flash attention v5 = R11's attn_v4 with LDS-pipe diet:
// (1) 16-lane reductions via DPP row_ror (no ds_bpermute), (2) qh*vl QK term
// and the whole Vn_l plane deleted (ql*vh kept for score precision),
// (3) softmax in exp2 domain (log2e folded into Q prescale). LDS 32 KB.
// ---------------------------------------------------------------------------
__global__ __launch_bounds__(256) void attn_v5(
    const u16* __restrict__ Qh_g, const u16* __restrict__ Ql_g,
    const u16* __restrict__ Vnh_g, const u16* __restrict__ Vth_g,
    u16* __restrict__ Ch, u16* __restrict__ Cl)
{
    __shared__ u16 Vn_h[64][64];                 // [u][s^((u&7)<<3)]
    __shared__ u16 Vt_h[64][64];                 // [s][u^((s&7)<<3)]
    __shared__ unsigned Ps[128][32];             // [t][(u&31)^((t&7)<<2)]

    const int tid = threadIdx.x;
    const int w = tid >> 6, lane = tid & 63;
    const int lg = lane >> 4, ln = lane & 15;
    const int ttile = blockIdx.x & 31;
    const int bh = blockIdx.x >> 5;
    const int t0 = ttile * 128;
    const size_t base = (size_t)bh * TSEQ * HS;
    const u16* Qph = Qh_g + base;
    const u16* Qpl = Ql_g + base;
    const u16* Vph = Vnh_g + base;
    const u16* Vth = Vth_g + base;   // [s][u], row stride TSEQ

    bf16x8 qh[2][2], ql[2][2];
    #pragma unroll
    for (int ti = 0; ti < 2; ++ti)
        #pragma unroll
        for (int kk = 0; kk < 2; ++kk) {
            int trow = t0 + w * 32 + ti * 16 + ln;
            size_t off = (size_t)trow * HS + kk * 32 + lg * 8;
            qh[ti][kk] = *(const bf16x8*)(Qph + off);
            ql[ti][kk] = *(const bf16x8*)(Qpl + off);
        }

    f32x4 o[2][4];
    float m[2][4], lsum[2][4];
    #pragma unroll
    for (int ti = 0; ti < 2; ++ti)
        #pragma unroll
        for (int j = 0; j < 4; ++j) {
            o[ti][j] = (f32x4){0.f, 0.f, 0.f, 0.f};
            m[ti][j] = -1e30f;
            lsum[ti][j] = 0.f;
        }

    int u_lo = t0 - CTX; if (u_lo < 0) u_lo = 0;
    int u_hi = t0 + 128 + CTX; if (u_hi > TSEQ) u_hi = TSEQ;

    // staging geometry: each thread covers rows sr and sr+32 of each plane
    const int sr = tid >> 3;            // 0..31
    const int c8 = (tid & 7) * 8;
    const int wcA = c8 ^ ((sr & 7) << 3);

    bf16x8 vn0h, vn1h, vt0h, vt1h;      // named prefetch regs
    #define VL(u0v)                                                             \
        vn0h = *(const bf16x8*)(Vph + (size_t)((u0v) + sr) * HS + c8);          \
        vn1h = *(const bf16x8*)(Vph + (size_t)((u0v) + sr + 32) * HS + c8);     \
        vt0h = *(const bf16x8*)(Vth + (size_t)sr * TSEQ + (u0v) + c8);          \
        vt1h = *(const bf16x8*)(Vth + (size_t)(sr + 32) * TSEQ + (u0v) + c8);

    VL(u_lo);

    for (int u0 = u_lo; u0 < u_hi; u0 += 64) {
        __syncthreads();
        *(bf16x8*)&Vn_h[sr][wcA]      = vn0h;
        *(bf16x8*)&Vn_h[sr + 32][wcA] = vn1h;
        *(bf16x8*)&Vt_h[sr][wcA]      = vt0h;
        *(bf16x8*)&Vt_h[sr + 32][wcA] = vt1h;
        __syncthreads();
        if (u0 + 64 < u_hi) { VL(u0 + 64); }

        // ---- scores: S[t][u] = sum_s Q[t][s] V[u][s]  (Q split, V hi)
        f32x4 s[2][4];
        #pragma unroll
        for (int ti = 0; ti < 2; ++ti)
            #pragma unroll
            for (int j = 0; j < 4; ++j)
                s[ti][j] = (f32x4){0.f, 0.f, 0.f, 0.f};

        #pragma unroll
        for (int kk = 0; kk < 2; ++kk) {
            const int fc = (kk * 32 + lg * 8) ^ ((ln & 7) << 3);
            bf16x8 vh[4];
            #pragma unroll
            for (int uj = 0; uj < 4; ++uj)
                vh[uj] = *(const bf16x8*)&Vn_h[uj * 16 + ln][fc];
            #pragma unroll
            for (int ti = 0; ti < 2; ++ti)
                #pragma unroll
                for (int uj = 0; uj < 4; ++uj) {
                    s[ti][uj] = MFMA(qh[ti][kk], vh[uj], s[ti][uj]);
                    s[ti][uj] = MFMA(ql[ti][kk], vh[uj], s[ti][uj]);
                }
        }

        // ---- band mask
        bool needmask = ((t0 + 127 - u0) > CTX) || ((u0 + 63 - t0) > CTX);
        if (needmask) {
            #pragma unroll
            for (int ti = 0; ti < 2; ++ti)
                #pragma unroll
                for (int uj = 0; uj < 4; ++uj)
                    #pragma unroll
                    for (int r = 0; r < 4; ++r) {
                        int t = t0 + w * 32 + ti * 16 + lg * 4 + r;
                        int u = u0 + uj * 16 + ln;
                        int d = t - u; if (d < 0) d = -d;
                        if (d > CTX) s[ti][uj][r] = -1e30f;
                    }
        }

        // ---- online softmax per row (exp2 domain, DPP reductions)
        float scl[2][4];
        #pragma unroll
        for (int ti = 0; ti < 2; ++ti)
            #pragma unroll
            for (int r = 0; r < 4; ++r) {
                float rm = fmaxf(fmaxf(s[ti][0][r], s[ti][1][r]),
                                 fmaxf(s[ti][2][r], s[ti][3][r]));
                rm = row16_max(rm);
                float mn = fmaxf(m[ti][r], rm);
                float sc2 = exp2f(m[ti][r] - mn);
                m[ti][r] = mn;
                scl[ti][r] = sc2;
                float rs = 0.f;
                #pragma unroll
                for (int uj = 0; uj < 4; ++uj) {
                    float p = exp2f(s[ti][uj][r] - mn);
                    s[ti][uj][r] = p;
                    rs += p;
                }
                rs = row16_sum(rs);
                lsum[ti][r] = lsum[ti][r] * sc2 + rs;
            }

        // ---- rescale running O
        #pragma unroll
        for (int ti = 0; ti < 2; ++ti)
            #pragma unroll
            for (int sj = 0; sj < 4; ++sj)
                #pragma unroll
                for (int r = 0; r < 4; ++r)
                    o[ti][sj][r] *= scl[ti][r];

        // ---- PV in two u-halves; P bf16 (dup'd halves), same strip as R11
        #pragma unroll
        for (int kk = 0; kk < 2; ++kk) {
            #pragma unroll
            for (int ti = 0; ti < 2; ++ti)
                #pragma unroll
                for (int u2 = 0; u2 < 2; ++u2) {
                    int uj = kk * 2 + u2;
                    #pragma unroll
                    for (int r = 0; r < 4; ++r) {
                        int trow = w * 32 + ti * 16 + lg * 4 + r;
                        int ucol = (u2 * 16 + ln) ^ ((trow & 7) << 2);
                        Ps[trow][ucol] = bf16dup(s[ti][uj][r]);
                    }
                }

            bf16x8 ph[2], vth4[4];
            #pragma unroll
            for (int ti = 0; ti < 2; ++ti) {
                int prow = w * 32 + ti * 16 + ln;
                int sw = (ln & 7) << 2;
                uint4 q0 = *(const uint4*)&Ps[prow][(lg * 8) ^ sw];
                uint4 q1 = *(const uint4*)&Ps[prow][(lg * 8 + 4) ^ sw];
                union { unsigned u[4]; bf16x8 v; } H;
                H.u[0] = __builtin_amdgcn_perm(q0.y, q0.x, 0x05040100u);
                H.u[1] = __builtin_amdgcn_perm(q0.w, q0.z, 0x05040100u);
                H.u[2] = __builtin_amdgcn_perm(q1.y, q1.x, 0x05040100u);
                H.u[3] = __builtin_amdgcn_perm(q1.w, q1.z, 0x05040100u);
                ph[ti] = H.v;
            }
            const int fct = (kk * 32 + lg * 8) ^ ((ln & 7) << 3);
            #pragma unroll
            for (int sj = 0; sj < 4; ++sj)
                vth4[sj] = *(const bf16x8*)&Vt_h[sj * 16 + ln][fct];
            #pragma unroll
            for (int ti = 0; ti < 2; ++ti)
                #pragma unroll
                for (int sj = 0; sj < 4; ++sj)
                    o[ti][sj] = MFMA(ph[ti], vth4[sj], o[ti][sj]);
        }
    }
    #undef VL

    // ---- epilogue: C split bf16, layout [b][t][h*64+s]
    const int b = bh >> 3, h = bh & 7;
    #pragma unroll
    for (int ti = 0; ti < 2; ++ti)
        #pragma unroll
        for (int r = 0; r < 4; ++r) {
            float inv = 1.f / lsum[ti][r];
            int t = t0 + w * 32 + ti * 16 + lg * 4 + r;
            #pragma unroll
            for (int sj = 0; sj < 4; ++sj) {
                int ss = sj * 16 + ln;
                float val = o[ti][sj][r] * inv;
                size_t off = ((size_t)(b * TSEQ + t)) * DM + h * HS + ss;
                u16 hb = f2bf(val);
                Ch[off] = hb;
                Cl[off] = f2bf(val - bf2f(hb));
            }
        }
}

// ---------------------------------------------------------------------------
extern "C" void kernel_launch(void* const* d_in, const int* in_sizes, int n_in,
                              void* d_out, int out_size, void* d_ws, size_t ws_size,
                              hipStream_t stream) {
    const float* X  = (const float*)d_in[0];
    const float* WQ = (const float*)d_in[1];
    const float* WV = (const float*)d_in[2];
    const float* WU = (const float*)d_in[3];
    float* out = (float*)d_out;

    const size_t SZ = 8388608;   // 8 MB region
    char* ws = (char*)d_ws;

    u16* Xh = (u16*)(ws);             // later reused as Ch
    u16* Xl = (u16*)(ws + SZ);        // later reused as Cl
    u16* Qh = (u16*)(ws + 2 * SZ);
    u16* Ql = (u16*)(ws + 3 * SZ);
    u16* Vh = (u16*)(ws + 4 * SZ);
    u16* Vl = (u16*)(ws + 5 * SZ);    // unused (kept for layout stability)
    u16* Vth = (u16*)(ws + 6 * SZ);
    char* wsw = ws + 8 * SZ;
    u16* WQt_h = (u16*)(wsw);
    u16* WQt_l = (u16*)(wsw + 524288);
    u16* WVt_h = (u16*)(wsw + 2 * 524288);
    u16* WVt_l = (u16*)(wsw + 3 * 524288);
    u16* WUt_h = (u16*)(wsw + 4 * 524288);
    u16* WUt_l = (u16*)(wsw + 5 * 524288);

    presplit_x<<<2048, 256, 0, stream>>>(X, Xh, Xl);
    presplit_w<<<3072, 256, 0, stream>>>(WQ, WV, WU, WQt_h, WQt_l,
                                         WVt_h, WVt_l, WUt_h, WUt_l);
    gemm_mfma<<<dim3(64, 16), 256, 0, stream>>>(
        Xh, Xl, WQt_h, WQt_l, WVt_h, WVt_l, Qh, Ql, Vh, Vl, nullptr, 0);
    transpose_v<<<1024, 256, 0, stream>>>(Vh, Vth);
    attn_v5<<<512, 256, 0, stream>>>(Qh, Ql, Vh, Vth, Xh, Xl);
    gemm_mfma<<<dim3(64, 8), 256, 0, stream>>>(
        Xh, Xl, WUt_h, WUt_l, nullptr, nullptr,
        nullptr, nullptr, nullptr, nullptr, out, 1);
}

// Round 15
// 104.088 us; speedup vs baseline: 1.6841x; 1.1263x over previous
//
#include <hip/hip_runtime.h>

#define TSEQ 4096
#define DM 512
#define NH 8
#define HS 64
#define CTX 256

typedef __attribute__((ext_vector_type(8))) short bf16x8;
typedef __attribute__((ext_vector_type(4))) float f32x4;
typedef unsigned short u16;
typedef unsigned long long ull;

__device__ __forceinline__ u16 f2bf(float x) {
    unsigned u = __float_as_uint(x);
    unsigned r = (u + 0x7fffu + ((u >> 16) & 1u)) >> 16;
    return (u16)r;
}
__device__ __forceinline__ float bf2f(u16 b) {
    return __uint_as_float(((unsigned)b) << 16);
}
// bf16(p) duplicated in both u16 halves — 1 instruction
__device__ __forceinline__ unsigned bf16dup(float p) {
    unsigned w;
    asm("v_cvt_pk_bf16_f32 %0, %1, %1" : "=v"(w) : "v"(p));
    return w;
}
// DPP row-rotate (16-lane row) reductions
template<int CTRL>
__device__ __forceinline__ float dpp_ror(float x) {
    int xi = __float_as_int(x);
    return __int_as_float(__builtin_amdgcn_update_dpp(xi, xi, CTRL, 0xf, 0xf, false));
}
__device__ __forceinline__ float row16_max(float v) {
    v = fmaxf(v, dpp_ror<0x121>(v));
    v = fmaxf(v, dpp_ror<0x122>(v));
    v = fmaxf(v, dpp_ror<0x124>(v));
    v = fmaxf(v, dpp_ror<0x128>(v));
    return v;
}
__device__ __forceinline__ float row16_sum(float v) {
    v += dpp_ror<0x121>(v);
    v += dpp_ror<0x122>(v);
    v += dpp_ror<0x124>(v);
    v += dpp_ror<0x128>(v);
    return v;
}
__device__ __forceinline__ void split8(const float* v, bf16x8& h, bf16x8& l) {
    #pragma unroll
    for (int i = 0; i < 8; ++i) {
        u16 hb = f2bf(v[i]);
        float hf = bf2f(hb);
        u16 lb = f2bf(v[i] - hf);
        h[i] = (short)hb;
        l[i] = (short)lb;
    }
}

#define MFMA(a, b, c) __builtin_amdgcn_mfma_f32_16x16x32_bf16((a), (b), (c), 0, 0, 0)

// ---------------------------------------------------------------------------
__global__ __launch_bounds__(256) void presplit_x(
    const float* __restrict__ X, u16* __restrict__ Xh, u16* __restrict__ Xl)
{
    size_t idx = ((size_t)blockIdx.x * 256 + threadIdx.x) * 8;
    float4 p0 = *(const float4*)(X + idx);
    float4 p1 = *(const float4*)(X + idx + 4);
    float v[8] = {p0.x, p0.y, p0.z, p0.w, p1.x, p1.y, p1.z, p1.w};
    bf16x8 h, l;
    split8(v, h, l);
    *(bf16x8*)(Xh + idx) = h;
    *(bf16x8*)(Xl + idx) = l;
}

// ---------------------------------------------------------------------------
// Pre-transpose weights, hi plane only (B-lo terms no longer used in GEMM).
// ---------------------------------------------------------------------------
__global__ __launch_bounds__(256) void presplit_w(
    const float* __restrict__ WQ, const float* __restrict__ WV,
    const float* __restrict__ WU,
    u16* __restrict__ WQt_h, u16* __restrict__ WVt_h, u16* __restrict__ WUt_h)
{
    int gidx = blockIdx.x * 256 + threadIdx.x;   // 0 .. 786431
    int a = gidx >> 18;                          // 0: WQ, 1: WV, 2: WU
    int r = gidx & 262143;
    float val;
    u16* dh;
    int dst;
    if (a < 2) {
        int h = r >> 15, s = (r >> 9) & 63, d = r & 511;
        const float* W = (a == 0) ? WQ : WV;
        val = W[h * 32768 + d * 64 + s];
        dst = h * 32768 + s * 512 + d;
        dh = (a == 0) ? WQt_h : WVt_h;
    } else {
        int n = r >> 9, k = r & 511;
        val = WU[k * 512 + n];
        dst = n * 512 + k;
        dh = WUt_h;
    }
    dh[dst] = f2bf(val);
}

// ---------------------------------------------------------------------------
// Split-bf16 MFMA GEMM, 2-term (A-hi·B-hi + A-lo·B-hi; B-lo dropped —
// |W_lo| <= lim*2^-9 ~ 1.5e-4 makes its contribution ~8e-4 absolute).
// 128x64 tile, K=512, BK=64. LDS 40 KB.
// ---------------------------------------------------------------------------
__global__ __launch_bounds__(256) void gemm_mfma(
    const u16* __restrict__ Ah_g, const u16* __restrict__ Al_g,
    const u16* __restrict__ B0h, const u16* __restrict__ B1h,
    u16* __restrict__ O0h, u16* __restrict__ O0l,
    u16* __restrict__ O1h,
    float* __restrict__ Of,
    int mode)
{
    __shared__ u16 Ah[128][64], Al[128][64];
    __shared__ u16 Bh[64][64];

    const int tid = threadIdx.x;
    const int w = tid >> 6, lane = tid & 63;
    const int lg = lane >> 4, ln = lane & 15;
    const int r0 = blockIdx.x * 128;
    const int y = blockIdx.y;

    const u16* Bsh;
    if (mode == 0) {
        Bsh = ((y < 8) ? B0h + (size_t)y * 32768 : B1h + (size_t)(y - 8) * 32768);
    } else {
        Bsh = B0h + (size_t)y * 64 * 512;
    }

    const int r_a = tid >> 3;
    const int kc  = tid & 7;
    const int wcol = (kc * 8) ^ ((r_a & 7) << 3);
    const size_t gA = (size_t)(r0 + r_a) * DM + kc * 8;
    const size_t gB = (size_t)r_a * 512 + kc * 8;

    bf16x8 a0h, a1h, a2h, a3h, a0l, a1l, a2l, a3l, b0h, b1h;

    #define GLOAD(k0)                                                   \
        a0h = *(const bf16x8*)(Ah_g + gA + (k0));                       \
        a1h = *(const bf16x8*)(Ah_g + gA + 32 * DM + (k0));             \
        a2h = *(const bf16x8*)(Ah_g + gA + 64 * DM + (k0));             \
        a3h = *(const bf16x8*)(Ah_g + gA + 96 * DM + (k0));             \
        a0l = *(const bf16x8*)(Al_g + gA + (k0));                       \
        a1l = *(const bf16x8*)(Al_g + gA + 32 * DM + (k0));             \
        a2l = *(const bf16x8*)(Al_g + gA + 64 * DM + (k0));             \
        a3l = *(const bf16x8*)(Al_g + gA + 96 * DM + (k0));             \
        b0h = *(const bf16x8*)(Bsh + gB + (k0));                        \
        b1h = *(const bf16x8*)(Bsh + gB + 32 * 512 + (k0));

    f32x4 acc[2][4];
    #pragma unroll
    for (int i = 0; i < 2; ++i)
        #pragma unroll
        for (int j = 0; j < 4; ++j)
            acc[i][j] = (f32x4){0.f, 0.f, 0.f, 0.f};

    GLOAD(0);

    for (int kt = 0; kt < 8; ++kt) {
        __syncthreads();
        *(bf16x8*)&Ah[r_a][wcol]      = a0h;
        *(bf16x8*)&Ah[r_a + 32][wcol] = a1h;
        *(bf16x8*)&Ah[r_a + 64][wcol] = a2h;
        *(bf16x8*)&Ah[r_a + 96][wcol] = a3h;
        *(bf16x8*)&Al[r_a][wcol]      = a0l;
        *(bf16x8*)&Al[r_a + 32][wcol] = a1l;
        *(bf16x8*)&Al[r_a + 64][wcol] = a2l;
        *(bf16x8*)&Al[r_a + 96][wcol] = a3l;
        *(bf16x8*)&Bh[r_a][wcol]      = b0h;
        *(bf16x8*)&Bh[r_a + 32][wcol] = b1h;
        __syncthreads();
        if (kt < 7) { GLOAD((kt + 1) * 64); }

        #pragma unroll
        for (int kk = 0; kk < 2; ++kk) {
            const int fc = (kk * 32 + lg * 8) ^ ((ln & 7) << 3);
            bf16x8 ah[2], al[2], bh2[4];
            #pragma unroll
            for (int ti = 0; ti < 2; ++ti) {
                ah[ti] = *(const bf16x8*)&Ah[w * 32 + ti * 16 + ln][fc];
                al[ti] = *(const bf16x8*)&Al[w * 32 + ti * 16 + ln][fc];
            }
            #pragma unroll
            for (int nj = 0; nj < 4; ++nj)
                bh2[nj] = *(const bf16x8*)&Bh[nj * 16 + ln][fc];
            #pragma unroll
            for (int ti = 0; ti < 2; ++ti)
                #pragma unroll
                for (int nj = 0; nj < 4; ++nj) {
                    acc[ti][nj] = MFMA(ah[ti], bh2[nj], acc[ti][nj]);
                    acc[ti][nj] = MFMA(al[ti], bh2[nj], acc[ti][nj]);
                }
        }
    }
    #undef GLOAD

    // Q prescale includes log2(e) so softmax can use exp2
    const float qscale = (mode == 0 && y < 8) ? 0.18033688f : 1.0f;
    #pragma unroll
    for (int ti = 0; ti < 2; ++ti)
        #pragma unroll
        for (int nj = 0; nj < 4; ++nj)
            #pragma unroll
            for (int r = 0; r < 4; ++r) {
                float val = acc[ti][nj][r] * qscale;
                int t = r0 + w * 32 + ti * 16 + lg * 4 + r;
                int n = nj * 16 + ln;
                if (mode == 0) {
                    int bh = (t >> 12) * NH + (y & 7);
                    size_t off = ((size_t)bh * TSEQ + (t & (TSEQ - 1))) * HS + n;
                    u16 hb = f2bf(val);
                    if (y < 8) {
                        O0h[off] = hb;
                        O0l[off] = f2bf(val - bf2f(hb));
                    } else {
                        O1h[off] = hb;   // V lo plane not needed
                    }
                } else {
                    Of[(size_t)t * DM + y * 64 + n] = val;
                }
            }
}

// ---------------------------------------------------------------------------
// V transpose (hi plane only): Vn_h[bh][u][s] -> Vt_h[bh][s][u]. LDS-tiled.
// ---------------------------------------------------------------------------
__global__ __launch_bounds__(256) void transpose_v(
    const u16* __restrict__ Vnh, u16* __restrict__ Vth)
{
    __shared__ u16 T[64][72];

    const int tid = threadIdx.x;
    const int bh = blockIdx.x >> 6;
    const int u0 = (blockIdx.x & 63) * 64;
    const size_t base = (size_t)bh * TSEQ * HS;

    const int lu = tid >> 2;
    const int s8 = (tid & 3) * 16;
    const int so = tid >> 2;
    const int u8 = (tid & 3) * 16;

    size_t goff = base + (size_t)(u0 + lu) * HS + s8;
    bf16x8 v0 = *(const bf16x8*)(Vnh + goff);
    bf16x8 v1 = *(const bf16x8*)(Vnh + goff + 8);
    *(bf16x8*)&T[lu][s8]     = v0;
    *(bf16x8*)&T[lu][s8 + 8] = v1;
    __syncthreads();
    union { u16 a[16]; bf16x8 v[2]; } out;
    #pragma unroll
    for (int e = 0; e < 16; ++e)
        out.a[e] = T[u8 + e][so];
    size_t doff = base + (size_t)so * TSEQ + u0 + u8;
    *(bf16x8*)(Vth + doff)     = out.v[0];
    *(bf16x8*)(Vth + doff + 8) = out.v[1];
}

// ---------------------------------------------------------------------------
// Banded flash attention v6 = R14's attn_v5 with the t-tile halved for
// occupancy: 64 t-rows/block (each wave owns 16 rows), grid 1024 = 4
// blocks/CU = 16 waves/CU. All swizzle/fragment formulas identical to v5
// (the ti dimension is deleted; t-base w*32+ti*16 -> w*16). LDS 24 KB.
// ---------------------------------------------------------------------------
__global__ __launch_bounds__(256) void attn_v6(
    const u16* __restrict__ Qh_g, const u16* __restrict__ Ql_g,
    const u16* __restrict__ Vnh_g, const u16* __restrict__ Vth_g,
    u16* __restrict__ Ch, u16* __restrict__ Cl)
{
    __shared__ u16 Vn_h[64][64];                 // [u][s^((u&7)<<3)]
    __shared__ u16 Vt_h[64][64];                 // [s][u^((s&7)<<3)]
    __shared__ unsigned Ps[4][16][32];           // per-wave [t][(u&31)^((t&7)<<2)]

    const int tid = threadIdx.x;
    const int w = tid >> 6, lane = tid & 63;
    const int lg = lane >> 4, ln = lane & 15;
    const int ttile = blockIdx.x & 63;
    const int bh = blockIdx.x >> 6;
    const int t0 = ttile * 64;
    const size_t base = (size_t)bh * TSEQ * HS;
    const u16* Qph = Qh_g + base;
    const u16* Qpl = Ql_g + base;
    const u16* Vph = Vnh_g + base;
    const u16* Vth = Vth_g + base;   // [s][u], row stride TSEQ

    // Q fragments: wave w owns rows t0 + w*16 + 0..15 (prescaled log2e/8)
    bf16x8 qh[2], ql[2];
    #pragma unroll
    for (int kk = 0; kk < 2; ++kk) {
        size_t off = (size_t)(t0 + w * 16 + ln) * HS + kk * 32 + lg * 8;
        qh[kk] = *(const bf16x8*)(Qph + off);
        ql[kk] = *(const bf16x8*)(Qpl + off);
    }

    f32x4 o[4];
    float m[4], lsum[4];
    #pragma unroll
    for (int j = 0; j < 4; ++j) {
        o[j] = (f32x4){0.f, 0.f, 0.f, 0.f};
        m[j] = -1e30f;
        lsum[j] = 0.f;
    }

    int u_lo = t0 - CTX; if (u_lo < 0) u_lo = 0;
    int u_hi = t0 + 64 + CTX; if (u_hi > TSEQ) u_hi = TSEQ;

    // staging geometry: each thread covers rows sr and sr+32 of each plane
    const int sr = tid >> 3;            // 0..31
    const int c8 = (tid & 7) * 8;
    const int wcA = c8 ^ ((sr & 7) << 3);

    bf16x8 vn0h, vn1h, vt0h, vt1h;      // named prefetch regs
    #define VL(u0v)                                                             \
        vn0h = *(const bf16x8*)(Vph + (size_t)((u0v) + sr) * HS + c8);          \
        vn1h = *(const bf16x8*)(Vph + (size_t)((u0v) + sr + 32) * HS + c8);     \
        vt0h = *(const bf16x8*)(Vth + (size_t)sr * TSEQ + (u0v) + c8);          \
        vt1h = *(const bf16x8*)(Vth + (size_t)(sr + 32) * TSEQ + (u0v) + c8);

    VL(u_lo);

    for (int u0 = u_lo; u0 < u_hi; u0 += 64) {
        __syncthreads();
        *(bf16x8*)&Vn_h[sr][wcA]      = vn0h;
        *(bf16x8*)&Vn_h[sr + 32][wcA] = vn1h;
        *(bf16x8*)&Vt_h[sr][wcA]      = vt0h;
        *(bf16x8*)&Vt_h[sr + 32][wcA] = vt1h;
        __syncthreads();
        if (u0 + 64 < u_hi) { VL(u0 + 64); }

        // ---- scores: S[t][u] = sum_s Q[t][s] V[u][s]  (Q split, V hi)
        f32x4 s[4];
        #pragma unroll
        for (int j = 0; j < 4; ++j) s[j] = (f32x4){0.f, 0.f, 0.f, 0.f};

        #pragma unroll
        for (int kk = 0; kk < 2; ++kk) {
            const int fc = (kk * 32 + lg * 8) ^ ((ln & 7) << 3);
            bf16x8 vh[4];
            #pragma unroll
            for (int uj = 0; uj < 4; ++uj)
                vh[uj] = *(const bf16x8*)&Vn_h[uj * 16 + ln][fc];
            #pragma unroll
            for (int uj = 0; uj < 4; ++uj) {
                s[uj] = MFMA(qh[kk], vh[uj], s[uj]);
                s[uj] = MFMA(ql[kk], vh[uj], s[uj]);
            }
        }

        // ---- band mask
        bool needmask = ((t0 + 63 - u0) > CTX) || ((u0 + 63 - t0) > CTX);
        if (needmask) {
            #pragma unroll
            for (int uj = 0; uj < 4; ++uj)
                #pragma unroll
                for (int r = 0; r < 4; ++r) {
                    int t = t0 + w * 16 + lg * 4 + r;
                    int u = u0 + uj * 16 + ln;
                    int d = t - u; if (d < 0) d = -d;
                    if (d > CTX) s[uj][r] = -1e30f;
                }
        }

        // ---- online softmax per row (exp2 domain, DPP reductions)
        float scl[4];
        #pragma unroll
        for (int r = 0; r < 4; ++r) {
            float rm = fmaxf(fmaxf(s[0][r], s[1][r]), fmaxf(s[2][r], s[3][r]));
            rm = row16_max(rm);
            float mn = fmaxf(m[r], rm);
            float sc2 = exp2f(m[r] - mn);
            m[r] = mn;
            scl[r] = sc2;
            float rs = 0.f;
            #pragma unroll
            for (int uj = 0; uj < 4; ++uj) {
                float p = exp2f(s[uj][r] - mn);
                s[uj][r] = p;
                rs += p;
            }
            rs = row16_sum(rs);
            lsum[r] = lsum[r] * sc2 + rs;
        }

        // ---- rescale running O
        #pragma unroll
        for (int sj = 0; sj < 4; ++sj)
            #pragma unroll
            for (int r = 0; r < 4; ++r)
                o[sj][r] *= scl[r];

        // ---- PV in two u-halves; P bf16 (dup'd halves), per-wave strip
        #pragma unroll
        for (int kk = 0; kk < 2; ++kk) {
            #pragma unroll
            for (int u2 = 0; u2 < 2; ++u2) {
                int uj = kk * 2 + u2;
                #pragma unroll
                for (int r = 0; r < 4; ++r) {
                    int trow = lg * 4 + r;
                    int ucol = (u2 * 16 + ln) ^ ((trow & 7) << 2);
                    Ps[w][trow][ucol] = bf16dup(s[uj][r]);
                }
            }

            bf16x8 ph, vth4[4];
            {
                int sw = (ln & 7) << 2;
                uint4 q0 = *(const uint4*)&Ps[w][ln][(lg * 8) ^ sw];
                uint4 q1 = *(const uint4*)&Ps[w][ln][(lg * 8 + 4) ^ sw];
                union { unsigned u[4]; bf16x8 v; } H;
                H.u[0] = __builtin_amdgcn_perm(q0.y, q0.x, 0x05040100u);
                H.u[1] = __builtin_amdgcn_perm(q0.w, q0.z, 0x05040100u);
                H.u[2] = __builtin_amdgcn_perm(q1.y, q1.x, 0x05040100u);
                H.u[3] = __builtin_amdgcn_perm(q1.w, q1.z, 0x05040100u);
                ph = H.v;
            }
            const int fct = (kk * 32 + lg * 8) ^ ((ln & 7) << 3);
            #pragma unroll
            for (int sj = 0; sj < 4; ++sj)
                vth4[sj] = *(const bf16x8*)&Vt_h[sj * 16 + ln][fct];
            #pragma unroll
            for (int sj = 0; sj < 4; ++sj)
                o[sj] = MFMA(ph, vth4[sj], o[sj]);
        }
    }
    #undef VL

    // ---- epilogue: C split bf16, layout [b][t][h*64+s]
    const int b = bh >> 3, h = bh & 7;
    #pragma unroll
    for (int r = 0; r < 4; ++r) {
        float inv = 1.f / lsum[r];
        int t = t0 + w * 16 + lg * 4 + r;
        #pragma unroll
        for (int sj = 0; sj < 4; ++sj) {
            int ss = sj * 16 + ln;
            float val = o[sj][r] * inv;
            size_t off = ((size_t)(b * TSEQ + t)) * DM + h * HS + ss;
            u16 hb = f2bf(val);
            Ch[off] = hb;
            Cl[off] = f2bf(val - bf2f(hb));
        }
    }
}

// ---------------------------------------------------------------------------
extern "C" void kernel_launch(void* const* d_in, const int* in_sizes, int n_in,
                              void* d_out, int out_size, void* d_ws, size_t ws_size,
                              hipStream_t stream) {
    const float* X  = (const float*)d_in[0];
    const float* WQ = (const float*)d_in[1];
    const float* WV = (const float*)d_in[2];
    const float* WU = (const float*)d_in[3];
    float* out = (float*)d_out;

    const size_t SZ = 8388608;   // 8 MB region
    char* ws = (char*)d_ws;

    u16* Xh = (u16*)(ws);             // later reused as Ch
    u16* Xl = (u16*)(ws + SZ);        // later reused as Cl
    u16* Qh = (u16*)(ws + 2 * SZ);
    u16* Ql = (u16*)(ws + 3 * SZ);
    u16* Vh = (u16*)(ws + 4 * SZ);
    u16* Vth = (u16*)(ws + 6 * SZ);
    char* wsw = ws + 8 * SZ;
    u16* WQt_h = (u16*)(wsw);
    u16* WVt_h = (u16*)(wsw + 524288);
    u16* WUt_h = (u16*)(wsw + 2 * 524288);

    presplit_x<<<2048, 256, 0, stream>>>(X, Xh, Xl);
    presplit_w<<<3072, 256, 0, stream>>>(WQ, WV, WU, WQt_h, WVt_h, WUt_h);
    gemm_mfma<<<dim3(64, 16), 256, 0, stream>>>(
        Xh, Xl, WQt_h, WVt_h, Qh, Ql, Vh, nullptr, 0);
    transpose_v<<<1024, 256, 0, stream>>>(Vh, Vth);
    attn_v6<<<1024, 256, 0, stream>>>(Qh, Ql, Vh, Vth, Xh, Xl);
    gemm_mfma<<<dim3(64, 8), 256, 0, stream>>>(
        Xh, Xl, WUt_h, nullptr, nullptr, nullptr, nullptr, out, 1);
}

// Round 16
// 93.707 us; speedup vs baseline: 1.8706x; 1.1108x over previous
//
#include <hip/hip_runtime.h>

#define TSEQ 4096
#define DM 512
#define NH 8
#define HS 64
#define CTX 256

typedef __attribute__((ext_vector_type(8))) short bf16x8;
typedef __attribute__((ext_vector_type(4))) float f32x4;
typedef unsigned short u16;
typedef unsigned long long ull;

__device__ __forceinline__ u16 f2bf(float x) {
    unsigned u = __float_as_uint(x);
    unsigned r = (u + 0x7fffu + ((u >> 16) & 1u)) >> 16;
    return (u16)r;
}
__device__ __forceinline__ float bf2f(u16 b) {
    return __uint_as_float(((unsigned)b) << 16);
}
__device__ __forceinline__ unsigned bf16dup(float p) {
    unsigned w;
    asm("v_cvt_pk_bf16_f32 %0, %1, %1" : "=v"(w) : "v"(p));
    return w;
}
template<int CTRL>
__device__ __forceinline__ float dpp_ror(float x) {
    int xi = __float_as_int(x);
    return __int_as_float(__builtin_amdgcn_update_dpp(xi, xi, CTRL, 0xf, 0xf, false));
}
__device__ __forceinline__ float row16_max(float v) {
    v = fmaxf(v, dpp_ror<0x121>(v));
    v = fmaxf(v, dpp_ror<0x122>(v));
    v = fmaxf(v, dpp_ror<0x124>(v));
    v = fmaxf(v, dpp_ror<0x128>(v));
    return v;
}
__device__ __forceinline__ float row16_sum(float v) {
    v += dpp_ror<0x121>(v);
    v += dpp_ror<0x122>(v);
    v += dpp_ror<0x124>(v);
    v += dpp_ror<0x128>(v);
    return v;
}

#define MFMA(a, b, c) __builtin_amdgcn_mfma_f32_16x16x32_bf16((a), (b), (c), 0, 0, 0)

// ---------------------------------------------------------------------------
// Pre-split X: hi plane only (gemm0 is 1-term; Xl had no other consumer).
// ---------------------------------------------------------------------------
__global__ __launch_bounds__(256) void presplit_x(
    const float* __restrict__ X, u16* __restrict__ Xh)
{
    size_t idx = ((size_t)blockIdx.x * 256 + threadIdx.x) * 8;
    float4 p0 = *(const float4*)(X + idx);
    float4 p1 = *(const float4*)(X + idx + 4);
    float v[8] = {p0.x, p0.y, p0.z, p0.w, p1.x, p1.y, p1.z, p1.w};
    bf16x8 h;
    #pragma unroll
    for (int i = 0; i < 8; ++i) h[i] = (short)f2bf(v[i]);
    *(bf16x8*)(Xh + idx) = h;
}

// ---------------------------------------------------------------------------
// Pre-transpose weights, hi plane only.
// ---------------------------------------------------------------------------
__global__ __launch_bounds__(256) void presplit_w(
    const float* __restrict__ WQ, const float* __restrict__ WV,
    const float* __restrict__ WU,
    u16* __restrict__ WQt_h, u16* __restrict__ WVt_h, u16* __restrict__ WUt_h)
{
    int gidx = blockIdx.x * 256 + threadIdx.x;   // 0 .. 786431
    int a = gidx >> 18;                          // 0: WQ, 1: WV, 2: WU
    int r = gidx & 262143;
    float val;
    u16* dh;
    int dst;
    if (a < 2) {
        int h = r >> 15, s = (r >> 9) & 63, d = r & 511;
        const float* W = (a == 0) ? WQ : WV;
        val = W[h * 32768 + d * 64 + s];
        dst = h * 32768 + s * 512 + d;
        dh = (a == 0) ? WQt_h : WVt_h;
    } else {
        int n = r >> 9, k = r & 511;
        val = WU[k * 512 + n];
        dst = n * 512 + k;
        dh = WUt_h;
    }
    dh[dst] = f2bf(val);
}

// ---------------------------------------------------------------------------
// MFMA GEMM. mode 0 (QV proj): 1-term Ah·Bh (Q written split, V hi only).
// mode 1 (out proj): 2-term (Ah+Al)·Bh, f32 output. 128x64 tile, BK=64.
// ---------------------------------------------------------------------------
__global__ __launch_bounds__(256) void gemm_mfma(
    const u16* __restrict__ Ah_g, const u16* __restrict__ Al_g,
    const u16* __restrict__ B0h, const u16* __restrict__ B1h,
    u16* __restrict__ O0h, u16* __restrict__ O0l,
    u16* __restrict__ O1h,
    float* __restrict__ Of,
    int mode)
{
    __shared__ u16 Ah[128][64], Al[128][64];
    __shared__ u16 Bh[64][64];

    const int tid = threadIdx.x;
    const int w = tid >> 6, lane = tid & 63;
    const int lg = lane >> 4, ln = lane & 15;
    const int r0 = blockIdx.x * 128;
    const int y = blockIdx.y;

    const u16* Bsh;
    if (mode == 0) {
        Bsh = ((y < 8) ? B0h + (size_t)y * 32768 : B1h + (size_t)(y - 8) * 32768);
    } else {
        Bsh = B0h + (size_t)y * 64 * 512;
    }

    const int r_a = tid >> 3;
    const int kc  = tid & 7;
    const int wcol = (kc * 8) ^ ((r_a & 7) << 3);
    const size_t gA = (size_t)(r0 + r_a) * DM + kc * 8;
    const size_t gB = (size_t)r_a * 512 + kc * 8;

    bf16x8 a0h, a1h, a2h, a3h, a0l, a1l, a2l, a3l, b0h, b1h;

    #define GLOAD(k0)                                                   \
        a0h = *(const bf16x8*)(Ah_g + gA + (k0));                       \
        a1h = *(const bf16x8*)(Ah_g + gA + 32 * DM + (k0));             \
        a2h = *(const bf16x8*)(Ah_g + gA + 64 * DM + (k0));             \
        a3h = *(const bf16x8*)(Ah_g + gA + 96 * DM + (k0));             \
        b0h = *(const bf16x8*)(Bsh + gB + (k0));                        \
        b1h = *(const bf16x8*)(Bsh + gB + 32 * 512 + (k0));             \
        if (mode == 1) {                                                \
            a0l = *(const bf16x8*)(Al_g + gA + (k0));                   \
            a1l = *(const bf16x8*)(Al_g + gA + 32 * DM + (k0));         \
            a2l = *(const bf16x8*)(Al_g + gA + 64 * DM + (k0));         \
            a3l = *(const bf16x8*)(Al_g + gA + 96 * DM + (k0));         \
        }

    f32x4 acc[2][4];
    #pragma unroll
    for (int i = 0; i < 2; ++i)
        #pragma unroll
        for (int j = 0; j < 4; ++j)
            acc[i][j] = (f32x4){0.f, 0.f, 0.f, 0.f};

    GLOAD(0);

    for (int kt = 0; kt < 8; ++kt) {
        __syncthreads();
        *(bf16x8*)&Ah[r_a][wcol]      = a0h;
        *(bf16x8*)&Ah[r_a + 32][wcol] = a1h;
        *(bf16x8*)&Ah[r_a + 64][wcol] = a2h;
        *(bf16x8*)&Ah[r_a + 96][wcol] = a3h;
        *(bf16x8*)&Bh[r_a][wcol]      = b0h;
        *(bf16x8*)&Bh[r_a + 32][wcol] = b1h;
        if (mode == 1) {
            *(bf16x8*)&Al[r_a][wcol]      = a0l;
            *(bf16x8*)&Al[r_a + 32][wcol] = a1l;
            *(bf16x8*)&Al[r_a + 64][wcol] = a2l;
            *(bf16x8*)&Al[r_a + 96][wcol] = a3l;
        }
        __syncthreads();
        if (kt < 7) { GLOAD((kt + 1) * 64); }

        #pragma unroll
        for (int kk = 0; kk < 2; ++kk) {
            const int fc = (kk * 32 + lg * 8) ^ ((ln & 7) << 3);
            bf16x8 ah[2], bh2[4];
            #pragma unroll
            for (int ti = 0; ti < 2; ++ti)
                ah[ti] = *(const bf16x8*)&Ah[w * 32 + ti * 16 + ln][fc];
            #pragma unroll
            for (int nj = 0; nj < 4; ++nj)
                bh2[nj] = *(const bf16x8*)&Bh[nj * 16 + ln][fc];
            #pragma unroll
            for (int ti = 0; ti < 2; ++ti)
                #pragma unroll
                for (int nj = 0; nj < 4; ++nj)
                    acc[ti][nj] = MFMA(ah[ti], bh2[nj], acc[ti][nj]);
            if (mode == 1) {
                bf16x8 al[2];
                #pragma unroll
                for (int ti = 0; ti < 2; ++ti)
                    al[ti] = *(const bf16x8*)&Al[w * 32 + ti * 16 + ln][fc];
                #pragma unroll
                for (int ti = 0; ti < 2; ++ti)
                    #pragma unroll
                    for (int nj = 0; nj < 4; ++nj)
                        acc[ti][nj] = MFMA(al[ti], bh2[nj], acc[ti][nj]);
            }
        }
    }
    #undef GLOAD

    // Q prescale includes log2(e) so softmax can use exp2
    const float qscale = (mode == 0 && y < 8) ? 0.18033688f : 1.0f;
    #pragma unroll
    for (int ti = 0; ti < 2; ++ti)
        #pragma unroll
        for (int nj = 0; nj < 4; ++nj)
            #pragma unroll
            for (int r = 0; r < 4; ++r) {
                float val = acc[ti][nj][r] * qscale;
                int t = r0 + w * 32 + ti * 16 + lg * 4 + r;
                int n = nj * 16 + ln;
                if (mode == 0) {
                    int bh = (t >> 12) * NH + (y & 7);
                    size_t off = ((size_t)bh * TSEQ + (t & (TSEQ - 1))) * HS + n;
                    u16 hb = f2bf(val);
                    if (y < 8) {
                        O0h[off] = hb;
                        O0l[off] = f2bf(val - bf2f(hb));
                    } else {
                        O1h[off] = hb;   // V lo plane not needed
                    }
                } else {
                    Of[(size_t)t * DM + y * 64 + n] = val;
                }
            }
}

// ---------------------------------------------------------------------------
// V transpose (hi plane only): Vn_h[bh][u][s] -> Vt_h[bh][s][u]. LDS-tiled.
// ---------------------------------------------------------------------------
__global__ __launch_bounds__(256) void transpose_v(
    const u16* __restrict__ Vnh, u16* __restrict__ Vth)
{
    __shared__ u16 T[64][72];

    const int tid = threadIdx.x;
    const int bh = blockIdx.x >> 6;
    const int u0 = (blockIdx.x & 63) * 64;
    const size_t base = (size_t)bh * TSEQ * HS;

    const int lu = tid >> 2;
    const int s8 = (tid & 3) * 16;
    const int so = tid >> 2;
    const int u8 = (tid & 3) * 16;

    size_t goff = base + (size_t)(u0 + lu) * HS + s8;
    bf16x8 v0 = *(const bf16x8*)(Vnh + goff);
    bf16x8 v1 = *(const bf16x8*)(Vnh + goff + 8);
    *(bf16x8*)&T[lu][s8]     = v0;
    *(bf16x8*)&T[lu][s8 + 8] = v1;
    __syncthreads();
    union { u16 a[16]; bf16x8 v[2]; } out;
    #pragma unroll
    for (int e = 0; e < 16; ++e)
        out.a[e] = T[u8 + e][so];
    size_t doff = base + (size_t)so * TSEQ + u0 + u8;
    *(bf16x8*)(Vth + doff)     = out.v[0];
    *(bf16x8*)(Vth + doff + 8) = out.v[1];
}

// ---------------------------------------------------------------------------
// Banded flash attention v7 = R15's attn_v6 + XCD-aware block swizzle:
// swz=(bid&7)*128+(bid>>3) (1024%8==0, bijective) pins bh {2x,2x+1} to
// XCD x so the 2 MB V working set stays in that XCD's 4 MB L2.
// ---------------------------------------------------------------------------
__global__ __launch_bounds__(256) void attn_v7(
    const u16* __restrict__ Qh_g, const u16* __restrict__ Ql_g,
    const u16* __restrict__ Vnh_g, const u16* __restrict__ Vth_g,
    u16* __restrict__ Ch, u16* __restrict__ Cl)
{
    __shared__ u16 Vn_h[64][64];                 // [u][s^((u&7)<<3)]
    __shared__ u16 Vt_h[64][64];                 // [s][u^((s&7)<<3)]
    __shared__ unsigned Ps[4][16][32];           // per-wave [t][(u&31)^((t&7)<<2)]

    const int tid = threadIdx.x;
    const int w = tid >> 6, lane = tid & 63;
    const int lg = lane >> 4, ln = lane & 15;
    const int raw = blockIdx.x;
    const int swz = (raw & 7) * 128 + (raw >> 3);   // XCD-contiguous
    const int ttile = swz & 63;
    const int bh = swz >> 6;
    const int t0 = ttile * 64;
    const size_t base = (size_t)bh * TSEQ * HS;
    const u16* Qph = Qh_g + base;
    const u16* Qpl = Ql_g + base;
    const u16* Vph = Vnh_g + base;
    const u16* Vth = Vth_g + base;   // [s][u], row stride TSEQ

    // Q fragments: wave w owns rows t0 + w*16 + 0..15 (prescaled log2e/8)
    bf16x8 qh[2], ql[2];
    #pragma unroll
    for (int kk = 0; kk < 2; ++kk) {
        size_t off = (size_t)(t0 + w * 16 + ln) * HS + kk * 32 + lg * 8;
        qh[kk] = *(const bf16x8*)(Qph + off);
        ql[kk] = *(const bf16x8*)(Qpl + off);
    }

    f32x4 o[4];
    float m[4], lsum[4];
    #pragma unroll
    for (int j = 0; j < 4; ++j) {
        o[j] = (f32x4){0.f, 0.f, 0.f, 0.f};
        m[j] = -1e30f;
        lsum[j] = 0.f;
    }

    int u_lo = t0 - CTX; if (u_lo < 0) u_lo = 0;
    int u_hi = t0 + 64 + CTX; if (u_hi > TSEQ) u_hi = TSEQ;

    const int sr = tid >> 3;            // 0..31
    const int c8 = (tid & 7) * 8;
    const int wcA = c8 ^ ((sr & 7) << 3);

    bf16x8 vn0h, vn1h, vt0h, vt1h;
    #define VL(u0v)                                                             \
        vn0h = *(const bf16x8*)(Vph + (size_t)((u0v) + sr) * HS + c8);          \
        vn1h = *(const bf16x8*)(Vph + (size_t)((u0v) + sr + 32) * HS + c8);     \
        vt0h = *(const bf16x8*)(Vth + (size_t)sr * TSEQ + (u0v) + c8);          \
        vt1h = *(const bf16x8*)(Vth + (size_t)(sr + 32) * TSEQ + (u0v) + c8);

    VL(u_lo);

    for (int u0 = u_lo; u0 < u_hi; u0 += 64) {
        __syncthreads();
        *(bf16x8*)&Vn_h[sr][wcA]      = vn0h;
        *(bf16x8*)&Vn_h[sr + 32][wcA] = vn1h;
        *(bf16x8*)&Vt_h[sr][wcA]      = vt0h;
        *(bf16x8*)&Vt_h[sr + 32][wcA] = vt1h;
        __syncthreads();
        if (u0 + 64 < u_hi) { VL(u0 + 64); }

        // ---- scores: S[t][u] = sum_s Q[t][s] V[u][s]  (Q split, V hi)
        f32x4 s[4];
        #pragma unroll
        for (int j = 0; j < 4; ++j) s[j] = (f32x4){0.f, 0.f, 0.f, 0.f};

        #pragma unroll
        for (int kk = 0; kk < 2; ++kk) {
            const int fc = (kk * 32 + lg * 8) ^ ((ln & 7) << 3);
            bf16x8 vh[4];
            #pragma unroll
            for (int uj = 0; uj < 4; ++uj)
                vh[uj] = *(const bf16x8*)&Vn_h[uj * 16 + ln][fc];
            #pragma unroll
            for (int uj = 0; uj < 4; ++uj) {
                s[uj] = MFMA(qh[kk], vh[uj], s[uj]);
                s[uj] = MFMA(ql[kk], vh[uj], s[uj]);
            }
        }

        // ---- band mask
        bool needmask = ((t0 + 63 - u0) > CTX) || ((u0 + 63 - t0) > CTX);
        if (needmask) {
            #pragma unroll
            for (int uj = 0; uj < 4; ++uj)
                #pragma unroll
                for (int r = 0; r < 4; ++r) {
                    int t = t0 + w * 16 + lg * 4 + r;
                    int u = u0 + uj * 16 + ln;
                    int d = t - u; if (d < 0) d = -d;
                    if (d > CTX) s[uj][r] = -1e30f;
                }
        }

        // ---- online softmax per row (exp2 domain, DPP reductions)
        float scl[4];
        #pragma unroll
        for (int r = 0; r < 4; ++r) {
            float rm = fmaxf(fmaxf(s[0][r], s[1][r]), fmaxf(s[2][r], s[3][r]));
            rm = row16_max(rm);
            float mn = fmaxf(m[r], rm);
            float sc2 = exp2f(m[r] - mn);
            m[r] = mn;
            scl[r] = sc2;
            float rs = 0.f;
            #pragma unroll
            for (int uj = 0; uj < 4; ++uj) {
                float p = exp2f(s[uj][r] - mn);
                s[uj][r] = p;
                rs += p;
            }
            rs = row16_sum(rs);
            lsum[r] = lsum[r] * sc2 + rs;
        }

        // ---- rescale running O
        #pragma unroll
        for (int sj = 0; sj < 4; ++sj)
            #pragma unroll
            for (int r = 0; r < 4; ++r)
                o[sj][r] *= scl[r];

        // ---- PV in two u-halves; P bf16 (dup'd halves), per-wave strip
        #pragma unroll
        for (int kk = 0; kk < 2; ++kk) {
            #pragma unroll
            for (int u2 = 0; u2 < 2; ++u2) {
                int uj = kk * 2 + u2;
                #pragma unroll
                for (int r = 0; r < 4; ++r) {
                    int trow = lg * 4 + r;
                    int ucol = (u2 * 16 + ln) ^ ((trow & 7) << 2);
                    Ps[w][trow][ucol] = bf16dup(s[uj][r]);
                }
            }

            bf16x8 ph, vth4[4];
            {
                int sw = (ln & 7) << 2;
                uint4 q0 = *(const uint4*)&Ps[w][ln][(lg * 8) ^ sw];
                uint4 q1 = *(const uint4*)&Ps[w][ln][(lg * 8 + 4) ^ sw];
                union { unsigned u[4]; bf16x8 v; } H;
                H.u[0] = __builtin_amdgcn_perm(q0.y, q0.x, 0x05040100u);
                H.u[1] = __builtin_amdgcn_perm(q0.w, q0.z, 0x05040100u);
                H.u[2] = __builtin_amdgcn_perm(q1.y, q1.x, 0x05040100u);
                H.u[3] = __builtin_amdgcn_perm(q1.w, q1.z, 0x05040100u);
                ph = H.v;
            }
            const int fct = (kk * 32 + lg * 8) ^ ((ln & 7) << 3);
            #pragma unroll
            for (int sj = 0; sj < 4; ++sj)
                vth4[sj] = *(const bf16x8*)&Vt_h[sj * 16 + ln][fct];
            #pragma unroll
            for (int sj = 0; sj < 4; ++sj)
                o[sj] = MFMA(ph, vth4[sj], o[sj]);
        }
    }
    #undef VL

    // ---- epilogue: C split bf16, layout [b][t][h*64+s]
    const int b = bh >> 3, h = bh & 7;
    #pragma unroll
    for (int r = 0; r < 4; ++r) {
        float inv = 1.f / lsum[r];
        int t = t0 + w * 16 + lg * 4 + r;
        #pragma unroll
        for (int sj = 0; sj < 4; ++sj) {
            int ss = sj * 16 + ln;
            float val = o[sj][r] * inv;
            size_t off = ((size_t)(b * TSEQ + t)) * DM + h * HS + ss;
            u16 hb = f2bf(val);
            Ch[off] = hb;
            Cl[off] = f2bf(val - bf2f(hb));
        }
    }
}

// ---------------------------------------------------------------------------
extern "C" void kernel_launch(void* const* d_in, const int* in_sizes, int n_in,
                              void* d_out, int out_size, void* d_ws, size_t ws_size,
                              hipStream_t stream) {
    const float* X  = (const float*)d_in[0];
    const float* WQ = (const float*)d_in[1];
    const float* WV = (const float*)d_in[2];
    const float* WU = (const float*)d_in[3];
    float* out = (float*)d_out;

    const size_t SZ = 8388608;   // 8 MB region
    char* ws = (char*)d_ws;

    u16* Xh = (u16*)(ws);             // later reused as Ch
    u16* Cl = (u16*)(ws + SZ);        // attn's Cl plane (Xl no longer exists)
    u16* Qh = (u16*)(ws + 2 * SZ);
    u16* Ql = (u16*)(ws + 3 * SZ);
    u16* Vh = (u16*)(ws + 4 * SZ);
    u16* Vth = (u16*)(ws + 6 * SZ);
    char* wsw = ws + 8 * SZ;
    u16* WQt_h = (u16*)(wsw);
    u16* WVt_h = (u16*)(wsw + 524288);
    u16* WUt_h = (u16*)(wsw + 2 * 524288);

    presplit_x<<<2048, 256, 0, stream>>>(X, Xh);
    presplit_w<<<3072, 256, 0, stream>>>(WQ, WV, WU, WQt_h, WVt_h, WUt_h);
    gemm_mfma<<<dim3(64, 16), 256, 0, stream>>>(
        Xh, nullptr, WQt_h, WVt_h, Qh, Ql, Vh, nullptr, 0);
    transpose_v<<<1024, 256, 0, stream>>>(Vh, Vth);
    attn_v7<<<1024, 256, 0, stream>>>(Qh, Ql, Vh, Vth, Xh, Cl);
    gemm_mfma<<<dim3(64, 8), 256, 0, stream>>>(
        Xh, Cl, WUt_h, nullptr, nullptr, nullptr, nullptr, out, 1);
}

// Round 17
// 87.835 us; speedup vs baseline: 1.9957x; 1.0669x over previous
//
#include <hip/hip_runtime.h>

#define TSEQ 4096
#define DM 512
#define NH 8
#define HS 64
#define CTX 256

typedef __attribute__((ext_vector_type(8))) short bf16x8;
typedef __attribute__((ext_vector_type(4))) float f32x4;
typedef unsigned short u16;
typedef unsigned long long ull;

__device__ __forceinline__ u16 f2bf(float x) {
    unsigned u = __float_as_uint(x);
    unsigned r = (u + 0x7fffu + ((u >> 16) & 1u)) >> 16;
    return (u16)r;
}
__device__ __forceinline__ float bf2f(u16 b) {
    return __uint_as_float(((unsigned)b) << 16);
}
__device__ __forceinline__ unsigned bf16dup(float p) {
    unsigned w;
    asm("v_cvt_pk_bf16_f32 %0, %1, %1" : "=v"(w) : "v"(p));
    return w;
}
template<int CTRL>
__device__ __forceinline__ float dpp_ror(float x) {
    int xi = __float_as_int(x);
    return __int_as_float(__builtin_amdgcn_update_dpp(xi, xi, CTRL, 0xf, 0xf, false));
}
__device__ __forceinline__ float row16_max(float v) {
    v = fmaxf(v, dpp_ror<0x121>(v));
    v = fmaxf(v, dpp_ror<0x122>(v));
    v = fmaxf(v, dpp_ror<0x124>(v));
    v = fmaxf(v, dpp_ror<0x128>(v));
    return v;
}

#define MFMA(a, b, c) __builtin_amdgcn_mfma_f32_16x16x32_bf16((a), (b), (c), 0, 0, 0)

// ---------------------------------------------------------------------------
__global__ __launch_bounds__(256) void presplit_x(
    const float* __restrict__ X, u16* __restrict__ Xh)
{
    size_t idx = ((size_t)blockIdx.x * 256 + threadIdx.x) * 8;
    float4 p0 = *(const float4*)(X + idx);
    float4 p1 = *(const float4*)(X + idx + 4);
    float v[8] = {p0.x, p0.y, p0.z, p0.w, p1.x, p1.y, p1.z, p1.w};
    bf16x8 h;
    #pragma unroll
    for (int i = 0; i < 8; ++i) h[i] = (short)f2bf(v[i]);
    *(bf16x8*)(Xh + idx) = h;
}

// ---------------------------------------------------------------------------
__global__ __launch_bounds__(256) void presplit_w(
    const float* __restrict__ WQ, const float* __restrict__ WV,
    const float* __restrict__ WU,
    u16* __restrict__ WQt_h, u16* __restrict__ WVt_h, u16* __restrict__ WUt_h)
{
    int gidx = blockIdx.x * 256 + threadIdx.x;   // 0 .. 786431
    int a = gidx >> 18;                          // 0: WQ, 1: WV, 2: WU
    int r = gidx & 262143;
    float val;
    u16* dh;
    int dst;
    if (a < 2) {
        int h = r >> 15, s = (r >> 9) & 63, d = r & 511;
        const float* W = (a == 0) ? WQ : WV;
        val = W[h * 32768 + d * 64 + s];
        dst = h * 32768 + s * 512 + d;
        dh = (a == 0) ? WQt_h : WVt_h;
    } else {
        int n = r >> 9, k = r & 511;
        val = WU[k * 512 + n];
        dst = n * 512 + k;
        dh = WUt_h;
    }
    dh[dst] = f2bf(val);
}

// ---------------------------------------------------------------------------
// 1-term MFMA GEMM (Ah·Bh). mode 0: QV proj (Q split out, V hi only).
// mode 1: out proj, f32 output. 128x64 tile, BK=64, LDS 24 KB.
// ---------------------------------------------------------------------------
__global__ __launch_bounds__(256) void gemm_mfma(
    const u16* __restrict__ Ah_g,
    const u16* __restrict__ B0h, const u16* __restrict__ B1h,
    u16* __restrict__ O0h, u16* __restrict__ O0l,
    u16* __restrict__ O1h,
    float* __restrict__ Of,
    int mode)
{
    __shared__ u16 Ah[128][64];
    __shared__ u16 Bh[64][64];

    const int tid = threadIdx.x;
    const int w = tid >> 6, lane = tid & 63;
    const int lg = lane >> 4, ln = lane & 15;
    const int r0 = blockIdx.x * 128;
    const int y = blockIdx.y;

    const u16* Bsh;
    if (mode == 0) {
        Bsh = ((y < 8) ? B0h + (size_t)y * 32768 : B1h + (size_t)(y - 8) * 32768);
    } else {
        Bsh = B0h + (size_t)y * 64 * 512;
    }

    const int r_a = tid >> 3;
    const int kc  = tid & 7;
    const int wcol = (kc * 8) ^ ((r_a & 7) << 3);
    const size_t gA = (size_t)(r0 + r_a) * DM + kc * 8;
    const size_t gB = (size_t)r_a * 512 + kc * 8;

    bf16x8 a0h, a1h, a2h, a3h, b0h, b1h;

    #define GLOAD(k0)                                                   \
        a0h = *(const bf16x8*)(Ah_g + gA + (k0));                       \
        a1h = *(const bf16x8*)(Ah_g + gA + 32 * DM + (k0));             \
        a2h = *(const bf16x8*)(Ah_g + gA + 64 * DM + (k0));             \
        a3h = *(const bf16x8*)(Ah_g + gA + 96 * DM + (k0));             \
        b0h = *(const bf16x8*)(Bsh + gB + (k0));                        \
        b1h = *(const bf16x8*)(Bsh + gB + 32 * 512 + (k0));

    f32x4 acc[2][4];
    #pragma unroll
    for (int i = 0; i < 2; ++i)
        #pragma unroll
        for (int j = 0; j < 4; ++j)
            acc[i][j] = (f32x4){0.f, 0.f, 0.f, 0.f};

    GLOAD(0);

    for (int kt = 0; kt < 8; ++kt) {
        __syncthreads();
        *(bf16x8*)&Ah[r_a][wcol]      = a0h;
        *(bf16x8*)&Ah[r_a + 32][wcol] = a1h;
        *(bf16x8*)&Ah[r_a + 64][wcol] = a2h;
        *(bf16x8*)&Ah[r_a + 96][wcol] = a3h;
        *(bf16x8*)&Bh[r_a][wcol]      = b0h;
        *(bf16x8*)&Bh[r_a + 32][wcol] = b1h;
        __syncthreads();
        if (kt < 7) { GLOAD((kt + 1) * 64); }

        #pragma unroll
        for (int kk = 0; kk < 2; ++kk) {
            const int fc = (kk * 32 + lg * 8) ^ ((ln & 7) << 3);
            bf16x8 ah[2], bh2[4];
            #pragma unroll
            for (int ti = 0; ti < 2; ++ti)
                ah[ti] = *(const bf16x8*)&Ah[w * 32 + ti * 16 + ln][fc];
            #pragma unroll
            for (int nj = 0; nj < 4; ++nj)
                bh2[nj] = *(const bf16x8*)&Bh[nj * 16 + ln][fc];
            #pragma unroll
            for (int ti = 0; ti < 2; ++ti)
                #pragma unroll
                for (int nj = 0; nj < 4; ++nj)
                    acc[ti][nj] = MFMA(ah[ti], bh2[nj], acc[ti][nj]);
        }
    }
    #undef GLOAD

    // Q prescale includes log2(e) so softmax can use exp2
    const float qscale = (mode == 0 && y < 8) ? 0.18033688f : 1.0f;
    #pragma unroll
    for (int ti = 0; ti < 2; ++ti)
        #pragma unroll
        for (int nj = 0; nj < 4; ++nj)
            #pragma unroll
            for (int r = 0; r < 4; ++r) {
                float val = acc[ti][nj][r] * qscale;
                int t = r0 + w * 32 + ti * 16 + lg * 4 + r;
                int n = nj * 16 + ln;
                if (mode == 0) {
                    int bh = (t >> 12) * NH + (y & 7);
                    size_t off = ((size_t)bh * TSEQ + (t & (TSEQ - 1))) * HS + n;
                    u16 hb = f2bf(val);
                    if (y < 8) {
                        O0h[off] = hb;
                        O0l[off] = f2bf(val - bf2f(hb));
                    } else {
                        O1h[off] = hb;
                    }
                } else {
                    Of[(size_t)t * DM + y * 64 + n] = val;
                }
            }
}

// ---------------------------------------------------------------------------
__global__ __launch_bounds__(256) void transpose_v(
    const u16* __restrict__ Vnh, u16* __restrict__ Vth)
{
    __shared__ u16 T[64][72];

    const int tid = threadIdx.x;
    const int bh = blockIdx.x >> 6;
    const int u0 = (blockIdx.x & 63) * 64;
    const size_t base = (size_t)bh * TSEQ * HS;

    const int lu = tid >> 2;
    const int s8 = (tid & 3) * 16;
    const int so = tid >> 2;
    const int u8 = (tid & 3) * 16;

    size_t goff = base + (size_t)(u0 + lu) * HS + s8;
    bf16x8 v0 = *(const bf16x8*)(Vnh + goff);
    bf16x8 v1 = *(const bf16x8*)(Vnh + goff + 8);
    *(bf16x8*)&T[lu][s8]     = v0;
    *(bf16x8*)&T[lu][s8 + 8] = v1;
    __syncthreads();
    union { u16 a[16]; bf16x8 v[2]; } out;
    #pragma unroll
    for (int e = 0; e < 16; ++e)
        out.a[e] = T[u8 + e][so];
    size_t doff = base + (size_t)so * TSEQ + u0 + u8;
    *(bf16x8*)(Vth + doff)     = out.v[0];
    *(bf16x8*)(Vth + doff + 8) = out.v[1];
}

// ---------------------------------------------------------------------------
// Banded flash attention v8 = R16's attn_v7 with:
// (1) lsum accumulated by the PV MFMA via a constant ones B-fragment
//     (row16_sum chain deleted; lsum read by one shfl/row at the end),
// (2) defer-max (THR=8 in exp2 domain): rescale only when some row's new
//     max exceeds m+8; P bounded by 2^8, all f32-safe,
// (3) C written hi-plane only (gemm1 is 1-term).
// ---------------------------------------------------------------------------
__global__ __launch_bounds__(256) void attn_v8(
    const u16* __restrict__ Qh_g, const u16* __restrict__ Ql_g,
    const u16* __restrict__ Vnh_g, const u16* __restrict__ Vth_g,
    u16* __restrict__ Ch)
{
    __shared__ u16 Vn_h[64][64];                 // [u][s^((u&7)<<3)]
    __shared__ u16 Vt_h[64][64];                 // [s][u^((s&7)<<3)]
    __shared__ unsigned Ps[4][16][32];           // per-wave [t][(u&31)^((t&7)<<2)]

    const int tid = threadIdx.x;
    const int w = tid >> 6, lane = tid & 63;
    const int lg = lane >> 4, ln = lane & 15;
    const int raw = blockIdx.x;
    const int swz = (raw & 7) * 128 + (raw >> 3);   // XCD-contiguous
    const int ttile = swz & 63;
    const int bh = swz >> 6;
    const int t0 = ttile * 64;
    const size_t base = (size_t)bh * TSEQ * HS;
    const u16* Qph = Qh_g + base;
    const u16* Qpl = Ql_g + base;
    const u16* Vph = Vnh_g + base;
    const u16* Vth = Vth_g + base;   // [s][u], row stride TSEQ

    // Q fragments: wave w owns rows t0 + w*16 + 0..15 (prescaled log2e/8)
    bf16x8 qh[2], ql[2];
    #pragma unroll
    for (int kk = 0; kk < 2; ++kk) {
        size_t off = (size_t)(t0 + w * 16 + ln) * HS + kk * 32 + lg * 8;
        qh[kk] = *(const bf16x8*)(Qph + off);
        ql[kk] = *(const bf16x8*)(Qpl + off);
    }

    // constant B-frag for the lsum column: B[64+ln][u] = (ln==0) ? 1 : 0
    bf16x8 ones_frag;
    #pragma unroll
    for (int e = 0; e < 8; ++e)
        ones_frag[e] = (ln == 0) ? (short)0x3F80 : (short)0;

    f32x4 o[4], o4;
    float m[4];
    #pragma unroll
    for (int j = 0; j < 4; ++j) {
        o[j] = (f32x4){0.f, 0.f, 0.f, 0.f};
        m[j] = -1e30f;
    }
    o4 = (f32x4){0.f, 0.f, 0.f, 0.f};

    int u_lo = t0 - CTX; if (u_lo < 0) u_lo = 0;
    int u_hi = t0 + 64 + CTX; if (u_hi > TSEQ) u_hi = TSEQ;

    const int sr = tid >> 3;            // 0..31
    const int c8 = (tid & 7) * 8;
    const int wcA = c8 ^ ((sr & 7) << 3);

    bf16x8 vn0h, vn1h, vt0h, vt1h;
    #define VL(u0v)                                                             \
        vn0h = *(const bf16x8*)(Vph + (size_t)((u0v) + sr) * HS + c8);          \
        vn1h = *(const bf16x8*)(Vph + (size_t)((u0v) + sr + 32) * HS + c8);     \
        vt0h = *(const bf16x8*)(Vth + (size_t)sr * TSEQ + (u0v) + c8);          \
        vt1h = *(const bf16x8*)(Vth + (size_t)(sr + 32) * TSEQ + (u0v) + c8);

    VL(u_lo);

    for (int u0 = u_lo; u0 < u_hi; u0 += 64) {
        __syncthreads();
        *(bf16x8*)&Vn_h[sr][wcA]      = vn0h;
        *(bf16x8*)&Vn_h[sr + 32][wcA] = vn1h;
        *(bf16x8*)&Vt_h[sr][wcA]      = vt0h;
        *(bf16x8*)&Vt_h[sr + 32][wcA] = vt1h;
        __syncthreads();
        if (u0 + 64 < u_hi) { VL(u0 + 64); }

        // ---- scores: S[t][u] = sum_s Q[t][s] V[u][s]  (Q split, V hi)
        f32x4 s[4];
        #pragma unroll
        for (int j = 0; j < 4; ++j) s[j] = (f32x4){0.f, 0.f, 0.f, 0.f};

        #pragma unroll
        for (int kk = 0; kk < 2; ++kk) {
            const int fc = (kk * 32 + lg * 8) ^ ((ln & 7) << 3);
            bf16x8 vh[4];
            #pragma unroll
            for (int uj = 0; uj < 4; ++uj)
                vh[uj] = *(const bf16x8*)&Vn_h[uj * 16 + ln][fc];
            #pragma unroll
            for (int uj = 0; uj < 4; ++uj) {
                s[uj] = MFMA(qh[kk], vh[uj], s[uj]);
                s[uj] = MFMA(ql[kk], vh[uj], s[uj]);
            }
        }

        // ---- band mask
        bool needmask = ((t0 + 63 - u0) > CTX) || ((u0 + 63 - t0) > CTX);
        if (needmask) {
            #pragma unroll
            for (int uj = 0; uj < 4; ++uj)
                #pragma unroll
                for (int r = 0; r < 4; ++r) {
                    int t = t0 + w * 16 + lg * 4 + r;
                    int u = u0 + uj * 16 + ln;
                    int d = t - u; if (d < 0) d = -d;
                    if (d > CTX) s[uj][r] = -1e30f;
                }
        }

        // ---- online softmax (exp2 domain, DPP max, defer-max THR=8)
        float rm[4];
        bool need = false;
        #pragma unroll
        for (int r = 0; r < 4; ++r) {
            float v = fmaxf(fmaxf(s[0][r], s[1][r]), fmaxf(s[2][r], s[3][r]));
            rm[r] = row16_max(v);
            need |= (rm[r] > m[r] + 8.f);
        }
        if (__any(need)) {
            #pragma unroll
            for (int r = 0; r < 4; ++r) {
                float mn = fmaxf(m[r], rm[r]);
                float sc2 = exp2f(m[r] - mn);
                m[r] = mn;
                o4[r] *= sc2;
                #pragma unroll
                for (int sj = 0; sj < 4; ++sj)
                    o[sj][r] *= sc2;
            }
        }
        #pragma unroll
        for (int r = 0; r < 4; ++r)
            #pragma unroll
            for (int uj = 0; uj < 4; ++uj)
                s[uj][r] = exp2f(s[uj][r] - m[r]);

        // ---- PV in two u-halves; P bf16 (dup'd halves); lsum via ones-frag
        #pragma unroll
        for (int kk = 0; kk < 2; ++kk) {
            #pragma unroll
            for (int u2 = 0; u2 < 2; ++u2) {
                int uj = kk * 2 + u2;
                #pragma unroll
                for (int r = 0; r < 4; ++r) {
                    int trow = lg * 4 + r;
                    int ucol = (u2 * 16 + ln) ^ ((trow & 7) << 2);
                    Ps[w][trow][ucol] = bf16dup(s[uj][r]);
                }
            }

            bf16x8 ph, vth4[4];
            {
                int sw = (ln & 7) << 2;
                uint4 q0 = *(const uint4*)&Ps[w][ln][(lg * 8) ^ sw];
                uint4 q1 = *(const uint4*)&Ps[w][ln][(lg * 8 + 4) ^ sw];
                union { unsigned u[4]; bf16x8 v; } H;
                H.u[0] = __builtin_amdgcn_perm(q0.y, q0.x, 0x05040100u);
                H.u[1] = __builtin_amdgcn_perm(q0.w, q0.z, 0x05040100u);
                H.u[2] = __builtin_amdgcn_perm(q1.y, q1.x, 0x05040100u);
                H.u[3] = __builtin_amdgcn_perm(q1.w, q1.z, 0x05040100u);
                ph = H.v;
            }
            const int fct = (kk * 32 + lg * 8) ^ ((ln & 7) << 3);
            #pragma unroll
            for (int sj = 0; sj < 4; ++sj)
                vth4[sj] = *(const bf16x8*)&Vt_h[sj * 16 + ln][fct];
            #pragma unroll
            for (int sj = 0; sj < 4; ++sj)
                o[sj] = MFMA(ph, vth4[sj], o[sj]);
            o4 = MFMA(ph, ones_frag, o4);
        }
    }
    #undef VL

    // ---- epilogue: lsum from ln==0 lanes, C hi-plane only
    const int b = bh >> 3, h = bh & 7;
    #pragma unroll
    for (int r = 0; r < 4; ++r) {
        float ls = __shfl(o4[r], (lane >> 4) << 4);
        float inv = 1.f / ls;
        int t = t0 + w * 16 + lg * 4 + r;
        #pragma unroll
        for (int sj = 0; sj < 4; ++sj) {
            int ss = sj * 16 + ln;
            float val = o[sj][r] * inv;
            size_t off = ((size_t)(b * TSEQ + t)) * DM + h * HS + ss;
            Ch[off] = f2bf(val);
        }
    }
}

// ---------------------------------------------------------------------------
extern "C" void kernel_launch(void* const* d_in, const int* in_sizes, int n_in,
                              void* d_out, int out_size, void* d_ws, size_t ws_size,
                              hipStream_t stream) {
    const float* X  = (const float*)d_in[0];
    const float* WQ = (const float*)d_in[1];
    const float* WV = (const float*)d_in[2];
    const float* WU = (const float*)d_in[3];
    float* out = (float*)d_out;

    const size_t SZ = 8388608;   // 8 MB region
    char* ws = (char*)d_ws;

    u16* Xh = (u16*)(ws);             // later reused as Ch
    u16* Qh = (u16*)(ws + 2 * SZ);
    u16* Ql = (u16*)(ws + 3 * SZ);
    u16* Vh = (u16*)(ws + 4 * SZ);
    u16* Vth = (u16*)(ws + 6 * SZ);
    char* wsw = ws + 8 * SZ;
    u16* WQt_h = (u16*)(wsw);
    u16* WVt_h = (u16*)(wsw + 524288);
    u16* WUt_h = (u16*)(wsw + 2 * 524288);

    presplit_x<<<2048, 256, 0, stream>>>(X, Xh);
    presplit_w<<<3072, 256, 0, stream>>>(WQ, WV, WU, WQt_h, WVt_h, WUt_h);
    gemm_mfma<<<dim3(64, 16), 256, 0, stream>>>(
        Xh, WQt_h, WVt_h, Qh, Ql, Vh, nullptr, 0);
    transpose_v<<<1024, 256, 0, stream>>>(Vh, Vth);
    attn_v8<<<1024, 256, 0, stream>>>(Qh, Ql, Vh, Vth, Xh);
    gemm_mfma<<<dim3(64, 8), 256, 0, stream>>>(
        Xh, WUt_h, nullptr, nullptr, nullptr, nullptr, out, 1);
}

// Round 18
// 78.224 us; speedup vs baseline: 2.2409x; 1.1229x over previous
//
#include <hip/hip_runtime.h>

#define TSEQ 4096
#define DM 512
#define NH 8
#define HS 64
#define CTX 256

typedef __attribute__((ext_vector_type(8))) short bf16x8;
typedef __attribute__((ext_vector_type(4))) float f32x4;
typedef unsigned short u16;
typedef unsigned long long ull;

__device__ __forceinline__ u16 f2bf(float x) {
    unsigned u = __float_as_uint(x);
    unsigned r = (u + 0x7fffu + ((u >> 16) & 1u)) >> 16;
    return (u16)r;
}
__device__ __forceinline__ float bf2f(u16 b) {
    return __uint_as_float(((unsigned)b) << 16);
}
__device__ __forceinline__ unsigned bf16dup(float p) {
    unsigned w;
    asm("v_cvt_pk_bf16_f32 %0, %1, %1" : "=v"(w) : "v"(p));
    return w;
}
template<int CTRL>
__device__ __forceinline__ float dpp_ror(float x) {
    int xi = __float_as_int(x);
    return __int_as_float(__builtin_amdgcn_update_dpp(xi, xi, CTRL, 0xf, 0xf, false));
}
__device__ __forceinline__ float row16_max(float v) {
    v = fmaxf(v, dpp_ror<0x121>(v));
    v = fmaxf(v, dpp_ror<0x122>(v));
    v = fmaxf(v, dpp_ror<0x124>(v));
    v = fmaxf(v, dpp_ror<0x128>(v));
    return v;
}

#define MFMA(a, b, c) __builtin_amdgcn_mfma_f32_16x16x32_bf16((a), (b), (c), 0, 0, 0)

// ---------------------------------------------------------------------------
__global__ __launch_bounds__(256) void presplit_x(
    const float* __restrict__ X, u16* __restrict__ Xh)
{
    size_t idx = ((size_t)blockIdx.x * 256 + threadIdx.x) * 8;
    float4 p0 = *(const float4*)(X + idx);
    float4 p1 = *(const float4*)(X + idx + 4);
    float v[8] = {p0.x, p0.y, p0.z, p0.w, p1.x, p1.y, p1.z, p1.w};
    bf16x8 h;
    #pragma unroll
    for (int i = 0; i < 8; ++i) h[i] = (short)f2bf(v[i]);
    *(bf16x8*)(Xh + idx) = h;
}

// ---------------------------------------------------------------------------
__global__ __launch_bounds__(256) void presplit_w(
    const float* __restrict__ WQ, const float* __restrict__ WV,
    const float* __restrict__ WU,
    u16* __restrict__ WQt_h, u16* __restrict__ WVt_h, u16* __restrict__ WUt_h)
{
    int gidx = blockIdx.x * 256 + threadIdx.x;   // 0 .. 786431
    int a = gidx >> 18;                          // 0: WQ, 1: WV, 2: WU
    int r = gidx & 262143;
    float val;
    u16* dh;
    int dst;
    if (a < 2) {
        int h = r >> 15, s = (r >> 9) & 63, d = r & 511;
        const float* W = (a == 0) ? WQ : WV;
        val = W[h * 32768 + d * 64 + s];
        dst = h * 32768 + s * 512 + d;
        dh = (a == 0) ? WQt_h : WVt_h;
    } else {
        int n = r >> 9, k = r & 511;
        val = WU[k * 512 + n];
        dst = n * 512 + k;
        dh = WUt_h;
    }
    dh[dst] = f2bf(val);
}

// ---------------------------------------------------------------------------
// 1-term MFMA GEMM (Ah·Bh). mode 0: QV proj — Q bf16 (prescaled), V written
// in BOTH layouts (natural Vh + transposed Vt via packed 8B stores: the
// output fragment's 4 consecutive t rows at fixed col s are contiguous in
// Vt[s][u]). mode 1: out proj, f32 output. 128x64 tile, BK=64, LDS 24 KB.
// ---------------------------------------------------------------------------
__global__ __launch_bounds__(256) void gemm_mfma(
    const u16* __restrict__ Ah_g,
    const u16* __restrict__ B0h, const u16* __restrict__ B1h,
    u16* __restrict__ O0h,          // mode0: Qh
    u16* __restrict__ O1h,          // mode0: Vh (natural)
    u16* __restrict__ O1t,          // mode0: Vt (transposed)
    float* __restrict__ Of,         // mode1: f32 out
    int mode)
{
    __shared__ u16 Ah[128][64];
    __shared__ u16 Bh[64][64];

    const int tid = threadIdx.x;
    const int w = tid >> 6, lane = tid & 63;
    const int lg = lane >> 4, ln = lane & 15;
    const int r0 = blockIdx.x * 128;
    const int y = blockIdx.y;

    const u16* Bsh;
    if (mode == 0) {
        Bsh = ((y < 8) ? B0h + (size_t)y * 32768 : B1h + (size_t)(y - 8) * 32768);
    } else {
        Bsh = B0h + (size_t)y * 64 * 512;
    }

    const int r_a = tid >> 3;
    const int kc  = tid & 7;
    const int wcol = (kc * 8) ^ ((r_a & 7) << 3);
    const size_t gA = (size_t)(r0 + r_a) * DM + kc * 8;
    const size_t gB = (size_t)r_a * 512 + kc * 8;

    bf16x8 a0h, a1h, a2h, a3h, b0h, b1h;

    #define GLOAD(k0)                                                   \
        a0h = *(const bf16x8*)(Ah_g + gA + (k0));                       \
        a1h = *(const bf16x8*)(Ah_g + gA + 32 * DM + (k0));             \
        a2h = *(const bf16x8*)(Ah_g + gA + 64 * DM + (k0));             \
        a3h = *(const bf16x8*)(Ah_g + gA + 96 * DM + (k0));             \
        b0h = *(const bf16x8*)(Bsh + gB + (k0));                        \
        b1h = *(const bf16x8*)(Bsh + gB + 32 * 512 + (k0));

    f32x4 acc[2][4];
    #pragma unroll
    for (int i = 0; i < 2; ++i)
        #pragma unroll
        for (int j = 0; j < 4; ++j)
            acc[i][j] = (f32x4){0.f, 0.f, 0.f, 0.f};

    GLOAD(0);

    for (int kt = 0; kt < 8; ++kt) {
        __syncthreads();
        *(bf16x8*)&Ah[r_a][wcol]      = a0h;
        *(bf16x8*)&Ah[r_a + 32][wcol] = a1h;
        *(bf16x8*)&Ah[r_a + 64][wcol] = a2h;
        *(bf16x8*)&Ah[r_a + 96][wcol] = a3h;
        *(bf16x8*)&Bh[r_a][wcol]      = b0h;
        *(bf16x8*)&Bh[r_a + 32][wcol] = b1h;
        __syncthreads();
        if (kt < 7) { GLOAD((kt + 1) * 64); }

        #pragma unroll
        for (int kk = 0; kk < 2; ++kk) {
            const int fc = (kk * 32 + lg * 8) ^ ((ln & 7) << 3);
            bf16x8 ah[2], bh2[4];
            #pragma unroll
            for (int ti = 0; ti < 2; ++ti)
                ah[ti] = *(const bf16x8*)&Ah[w * 32 + ti * 16 + ln][fc];
            #pragma unroll
            for (int nj = 0; nj < 4; ++nj)
                bh2[nj] = *(const bf16x8*)&Bh[nj * 16 + ln][fc];
            #pragma unroll
            for (int ti = 0; ti < 2; ++ti)
                #pragma unroll
                for (int nj = 0; nj < 4; ++nj)
                    acc[ti][nj] = MFMA(ah[ti], bh2[nj], acc[ti][nj]);
        }
    }
    #undef GLOAD

    // Q prescale includes log2(e) so softmax can use exp2
    const float qscale = (mode == 0 && y < 8) ? 0.18033688f : 1.0f;
    #pragma unroll
    for (int ti = 0; ti < 2; ++ti)
        #pragma unroll
        for (int nj = 0; nj < 4; ++nj) {
            u16 hb[4];
            #pragma unroll
            for (int r = 0; r < 4; ++r) {
                float val = acc[ti][nj][r] * qscale;
                hb[r] = f2bf(val);
                int t = r0 + w * 32 + ti * 16 + lg * 4 + r;
                int n = nj * 16 + ln;
                if (mode == 0) {
                    int bh = (t >> 12) * NH + (y & 7);
                    size_t off = ((size_t)bh * TSEQ + (t & (TSEQ - 1))) * HS + n;
                    if (y < 8) O0h[off] = hb[r];
                    else       O1h[off] = hb[r];
                } else {
                    Of[(size_t)t * DM + y * 64 + n] = val;
                }
            }
            if (mode == 0 && y >= 8) {
                // transposed packed store: Vt[bh][s=n][u = t..t+3]
                int t = r0 + w * 32 + ti * 16 + lg * 4;
                int n = nj * 16 + ln;
                int bh = (t >> 12) * NH + (y & 7);
                size_t off = (size_t)bh * TSEQ * HS + (size_t)n * TSEQ + (t & (TSEQ - 1));
                ull pk = (ull)hb[0] | ((ull)hb[1] << 16)
                       | ((ull)hb[2] << 32) | ((ull)hb[3] << 48);
                *(ull*)(O1t + off) = pk;
            }
        }
}

// ---------------------------------------------------------------------------
// Banded flash attention v9 = R17's attn_v8 with Q-lo dropped (Q plain
// bf16): QK is 8 MFMA/chunk, Ql buffer gone. Everything else identical.
// ---------------------------------------------------------------------------
__global__ __launch_bounds__(256) void attn_v9(
    const u16* __restrict__ Qh_g,
    const u16* __restrict__ Vnh_g, const u16* __restrict__ Vth_g,
    u16* __restrict__ Ch)
{
    __shared__ u16 Vn_h[64][64];                 // [u][s^((u&7)<<3)]
    __shared__ u16 Vt_h[64][64];                 // [s][u^((s&7)<<3)]
    __shared__ unsigned Ps[4][16][32];           // per-wave [t][(u&31)^((t&7)<<2)]

    const int tid = threadIdx.x;
    const int w = tid >> 6, lane = tid & 63;
    const int lg = lane >> 4, ln = lane & 15;
    const int raw = blockIdx.x;
    const int swz = (raw & 7) * 128 + (raw >> 3);   // XCD-contiguous
    const int ttile = swz & 63;
    const int bh = swz >> 6;
    const int t0 = ttile * 64;
    const size_t base = (size_t)bh * TSEQ * HS;
    const u16* Qph = Qh_g + base;
    const u16* Vph = Vnh_g + base;
    const u16* Vth = Vth_g + base;   // [s][u], row stride TSEQ

    // Q fragments: wave w owns rows t0 + w*16 + 0..15 (prescaled log2e/8)
    bf16x8 qh[2];
    #pragma unroll
    for (int kk = 0; kk < 2; ++kk) {
        size_t off = (size_t)(t0 + w * 16 + ln) * HS + kk * 32 + lg * 8;
        qh[kk] = *(const bf16x8*)(Qph + off);
    }

    // constant B-frag for the lsum column: B[64+ln][u] = (ln==0) ? 1 : 0
    bf16x8 ones_frag;
    #pragma unroll
    for (int e = 0; e < 8; ++e)
        ones_frag[e] = (ln == 0) ? (short)0x3F80 : (short)0;

    f32x4 o[4], o4;
    float m[4];
    #pragma unroll
    for (int j = 0; j < 4; ++j) {
        o[j] = (f32x4){0.f, 0.f, 0.f, 0.f};
        m[j] = -1e30f;
    }
    o4 = (f32x4){0.f, 0.f, 0.f, 0.f};

    int u_lo = t0 - CTX; if (u_lo < 0) u_lo = 0;
    int u_hi = t0 + 64 + CTX; if (u_hi > TSEQ) u_hi = TSEQ;

    const int sr = tid >> 3;            // 0..31
    const int c8 = (tid & 7) * 8;
    const int wcA = c8 ^ ((sr & 7) << 3);

    bf16x8 vn0h, vn1h, vt0h, vt1h;
    #define VL(u0v)                                                             \
        vn0h = *(const bf16x8*)(Vph + (size_t)((u0v) + sr) * HS + c8);          \
        vn1h = *(const bf16x8*)(Vph + (size_t)((u0v) + sr + 32) * HS + c8);     \
        vt0h = *(const bf16x8*)(Vth + (size_t)sr * TSEQ + (u0v) + c8);          \
        vt1h = *(const bf16x8*)(Vth + (size_t)(sr + 32) * TSEQ + (u0v) + c8);

    VL(u_lo);

    for (int u0 = u_lo; u0 < u_hi; u0 += 64) {
        __syncthreads();
        *(bf16x8*)&Vn_h[sr][wcA]      = vn0h;
        *(bf16x8*)&Vn_h[sr + 32][wcA] = vn1h;
        *(bf16x8*)&Vt_h[sr][wcA]      = vt0h;
        *(bf16x8*)&Vt_h[sr + 32][wcA] = vt1h;
        __syncthreads();
        if (u0 + 64 < u_hi) { VL(u0 + 64); }

        // ---- scores: S[t][u] = sum_s Q[t][s] V[u][s]  (bf16 Q, bf16 V)
        f32x4 s[4];
        #pragma unroll
        for (int j = 0; j < 4; ++j) s[j] = (f32x4){0.f, 0.f, 0.f, 0.f};

        #pragma unroll
        for (int kk = 0; kk < 2; ++kk) {
            const int fc = (kk * 32 + lg * 8) ^ ((ln & 7) << 3);
            bf16x8 vh[4];
            #pragma unroll
            for (int uj = 0; uj < 4; ++uj)
                vh[uj] = *(const bf16x8*)&Vn_h[uj * 16 + ln][fc];
            #pragma unroll
            for (int uj = 0; uj < 4; ++uj)
                s[uj] = MFMA(qh[kk], vh[uj], s[uj]);
        }

        // ---- band mask
        bool needmask = ((t0 + 63 - u0) > CTX) || ((u0 + 63 - t0) > CTX);
        if (needmask) {
            #pragma unroll
            for (int uj = 0; uj < 4; ++uj)
                #pragma unroll
                for (int r = 0; r < 4; ++r) {
                    int t = t0 + w * 16 + lg * 4 + r;
                    int u = u0 + uj * 16 + ln;
                    int d = t - u; if (d < 0) d = -d;
                    if (d > CTX) s[uj][r] = -1e30f;
                }
        }

        // ---- online softmax (exp2 domain, DPP max, defer-max THR=8)
        float rm[4];
        bool need = false;
        #pragma unroll
        for (int r = 0; r < 4; ++r) {
            float v = fmaxf(fmaxf(s[0][r], s[1][r]), fmaxf(s[2][r], s[3][r]));
            rm[r] = row16_max(v);
            need |= (rm[r] > m[r] + 8.f);
        }
        if (__any(need)) {
            #pragma unroll
            for (int r = 0; r < 4; ++r) {
                float mn = fmaxf(m[r], rm[r]);
                float sc2 = exp2f(m[r] - mn);
                m[r] = mn;
                o4[r] *= sc2;
                #pragma unroll
                for (int sj = 0; sj < 4; ++sj)
                    o[sj][r] *= sc2;
            }
        }
        #pragma unroll
        for (int r = 0; r < 4; ++r)
            #pragma unroll
            for (int uj = 0; uj < 4; ++uj)
                s[uj][r] = exp2f(s[uj][r] - m[r]);

        // ---- PV in two u-halves; P bf16 (dup'd halves); lsum via ones-frag
        #pragma unroll
        for (int kk = 0; kk < 2; ++kk) {
            #pragma unroll
            for (int u2 = 0; u2 < 2; ++u2) {
                int uj = kk * 2 + u2;
                #pragma unroll
                for (int r = 0; r < 4; ++r) {
                    int trow = lg * 4 + r;
                    int ucol = (u2 * 16 + ln) ^ ((trow & 7) << 2);
                    Ps[w][trow][ucol] = bf16dup(s[uj][r]);
                }
            }

            bf16x8 ph, vth4[4];
            {
                int sw = (ln & 7) << 2;
                uint4 q0 = *(const uint4*)&Ps[w][ln][(lg * 8) ^ sw];
                uint4 q1 = *(const uint4*)&Ps[w][ln][(lg * 8 + 4) ^ sw];
                union { unsigned u[4]; bf16x8 v; } H;
                H.u[0] = __builtin_amdgcn_perm(q0.y, q0.x, 0x05040100u);
                H.u[1] = __builtin_amdgcn_perm(q0.w, q0.z, 0x05040100u);
                H.u[2] = __builtin_amdgcn_perm(q1.y, q1.x, 0x05040100u);
                H.u[3] = __builtin_amdgcn_perm(q1.w, q1.z, 0x05040100u);
                ph = H.v;
            }
            const int fct = (kk * 32 + lg * 8) ^ ((ln & 7) << 3);
            #pragma unroll
            for (int sj = 0; sj < 4; ++sj)
                vth4[sj] = *(const bf16x8*)&Vt_h[sj * 16 + ln][fct];
            #pragma unroll
            for (int sj = 0; sj < 4; ++sj)
                o[sj] = MFMA(ph, vth4[sj], o[sj]);
            o4 = MFMA(ph, ones_frag, o4);
        }
    }
    #undef VL

    // ---- epilogue: lsum from ln==0 lanes, C hi-plane only
    const int b = bh >> 3, h = bh & 7;
    #pragma unroll
    for (int r = 0; r < 4; ++r) {
        float ls = __shfl(o4[r], (lane >> 4) << 4);
        float inv = 1.f / ls;
        int t = t0 + w * 16 + lg * 4 + r;
        #pragma unroll
        for (int sj = 0; sj < 4; ++sj) {
            int ss = sj * 16 + ln;
            float val = o[sj][r] * inv;
            size_t off = ((size_t)(b * TSEQ + t)) * DM + h * HS + ss;
            Ch[off] = f2bf(val);
        }
    }
}

// ---------------------------------------------------------------------------
extern "C" void kernel_launch(void* const* d_in, const int* in_sizes, int n_in,
                              void* d_out, int out_size, void* d_ws, size_t ws_size,
                              hipStream_t stream) {
    const float* X  = (const float*)d_in[0];
    const float* WQ = (const float*)d_in[1];
    const float* WV = (const float*)d_in[2];
    const float* WU = (const float*)d_in[3];
    float* out = (float*)d_out;

    const size_t SZ = 8388608;   // 8 MB region
    char* ws = (char*)d_ws;

    u16* Xh = (u16*)(ws);             // later reused as Ch
    u16* Qh = (u16*)(ws + 2 * SZ);
    u16* Vh = (u16*)(ws + 4 * SZ);
    u16* Vth = (u16*)(ws + 6 * SZ);
    char* wsw = ws + 8 * SZ;
    u16* WQt_h = (u16*)(wsw);
    u16* WVt_h = (u16*)(wsw + 524288);
    u16* WUt_h = (u16*)(wsw + 2 * 524288);

    presplit_x<<<2048, 256, 0, stream>>>(X, Xh);
    presplit_w<<<3072, 256, 0, stream>>>(WQ, WV, WU, WQt_h, WVt_h, WUt_h);
    gemm_mfma<<<dim3(64, 16), 256, 0, stream>>>(
        Xh, WQt_h, WVt_h, Qh, Vh, Vth, nullptr, 0);
    attn_v9<<<1024, 256, 0, stream>>>(Qh, Vh, Vth, Xh);
    gemm_mfma<<<dim3(64, 8), 256, 0, stream>>>(
        Xh, WUt_h, nullptr, nullptr, nullptr, nullptr, out, 1);
}